// Round 4
// baseline (1186.777 us; speedup 1.0000x reference)
//
#include <hip/hip_runtime.h>
#include <hip/hip_bf16.h>
#include <math.h>

#define N_USERS 50000
#define N_ITEMS 100000
#define N_NODES 150000
#define N_EDGES 2000000
#define EMBED 64
#define N_LAYERS 3
#define BATCH 8192

#define SCAN_CHUNK 1024
#define SCAN_NBLK ((N_NODES + SCAN_CHUNK - 1) / SCAN_CHUNK)  // 147

// ---------------- CSR build ----------------
__global__ __launch_bounds__(256) void k_count(const int* __restrict__ rows, int* __restrict__ cnt) {
    int e = (blockIdx.x * 256 + threadIdx.x) * 4;
    if (e + 3 < N_EDGES) {
        int4 r = *(const int4*)&rows[e];
        atomicAdd(&cnt[r.x], 1);
        atomicAdd(&cnt[r.y], 1);
        atomicAdd(&cnt[r.z], 1);
        atomicAdd(&cnt[r.w], 1);
    } else {
        for (int k = 0; k < 4; k++)
            if (e + k < N_EDGES) atomicAdd(&cnt[rows[e + k]], 1);
    }
}

__global__ __launch_bounds__(256) void k_scan_partial(const int* __restrict__ cnt,
                                                      int* __restrict__ partials) {
    int base = blockIdx.x * SCAN_CHUNK + threadIdx.x * 4;
    int v = 0;
    if (base + 3 < N_NODES) {
        int4 c = *(const int4*)&cnt[base];
        v = c.x + c.y + c.z + c.w;
    } else {
        for (int k = 0; k < 4; k++)
            if (base + k < N_NODES) v += cnt[base + k];
    }
    for (int o = 1; o < 64; o <<= 1) v += __shfl_xor(v, o);
    __shared__ int s[4];
    int wid = threadIdx.x >> 6, lane = threadIdx.x & 63;
    if (lane == 0) s[wid] = v;
    __syncthreads();
    if (threadIdx.x == 0) partials[blockIdx.x] = s[0] + s[1] + s[2] + s[3];
}

__global__ __launch_bounds__(256) void k_scan_blk(const int* __restrict__ partials,
                                                  int* __restrict__ blkoff) {
    int tid = threadIdx.x;
    int x = (tid < SCAN_NBLK) ? partials[tid] : 0;
    int v = x;
    int lane = tid & 63, wid = tid >> 6;
    for (int o = 1; o < 64; o <<= 1) {
        int t = __shfl_up(v, o);
        if (lane >= o) v += t;
    }
    __shared__ int ws[4];
    if (lane == 63) ws[wid] = v;
    __syncthreads();
    int add = 0;
    for (int w = 0; w < wid; w++) add += ws[w];
    if (tid < SCAN_NBLK) blkoff[tid] = add + v - x;      // exclusive prefix
}

__global__ __launch_bounds__(256) void k_scan_apply(const int* __restrict__ cnt,
                                                    const int* __restrict__ blkoff,
                                                    int* __restrict__ row_ptr,
                                                    int* __restrict__ cursor) {
    int tid = threadIdx.x;
    int base = blockIdx.x * SCAN_CHUNK + tid * 4;
    int c0 = 0, c1 = 0, c2 = 0, c3 = 0;
    if (base + 3 < N_NODES) {
        int4 c = *(const int4*)&cnt[base];
        c0 = c.x; c1 = c.y; c2 = c.z; c3 = c.w;
    } else {
        if (base     < N_NODES) c0 = cnt[base];
        if (base + 1 < N_NODES) c1 = cnt[base + 1];
        if (base + 2 < N_NODES) c2 = cnt[base + 2];
        if (base + 3 < N_NODES) c3 = cnt[base + 3];
    }
    int tsum = c0 + c1 + c2 + c3;
    int lane = tid & 63, wid = tid >> 6;
    int v = tsum;
    for (int o = 1; o < 64; o <<= 1) {
        int t = __shfl_up(v, o);
        if (lane >= o) v += t;
    }
    __shared__ int ws[4];
    if (lane == 63) ws[wid] = v;
    __syncthreads();
    int add = blkoff[blockIdx.x];
    for (int w = 0; w < wid; w++) add += ws[w];
    int excl = add + v - tsum;
    int p0 = excl, p1 = p0 + c0, p2 = p1 + c1, p3 = p2 + c2;
    if (base + 3 < N_NODES) {
        int4 rp = make_int4(p0, p1, p2, p3);
        *(int4*)&row_ptr[base] = rp;
        *(int4*)&cursor[base]  = rp;
    } else {
        int ps[4] = {p0, p1, p2, p3};
        for (int k = 0; k < 4; k++)
            if (base + k < N_NODES) { row_ptr[base + k] = ps[k]; cursor[base + k] = ps[k]; }
    }
    if (base < N_NODES && base + 4 >= N_NODES) {
        row_ptr[N_NODES] = p3 + c3;                      // total edge count
    }
}

// scatter edges as packed (col, val) int2 — one scattered cache line per edge
__global__ __launch_bounds__(256) void k_scatter(const int* __restrict__ rows,
                                                 const int* __restrict__ cols,
                                                 const float* __restrict__ vals,
                                                 int* __restrict__ cursor,
                                                 int2* __restrict__ edges) {
    int e = (blockIdx.x * 256 + threadIdx.x) * 4;
    if (e + 3 < N_EDGES) {
        int4   r = *(const int4*)&rows[e];
        int4   c = *(const int4*)&cols[e];
        float4 v = *(const float4*)&vals[e];
        int p;
        p = atomicAdd(&cursor[r.x], 1); edges[p] = make_int2(c.x, __float_as_int(v.x));
        p = atomicAdd(&cursor[r.y], 1); edges[p] = make_int2(c.y, __float_as_int(v.y));
        p = atomicAdd(&cursor[r.z], 1); edges[p] = make_int2(c.z, __float_as_int(v.z));
        p = atomicAdd(&cursor[r.w], 1); edges[p] = make_int2(c.w, __float_as_int(v.w));
    } else {
        for (int k = 0; k < 4; k++) {
            int ee = e + k;
            if (ee < N_EDGES) {
                int r = rows[ee];
                int p = atomicAdd(&cursor[r], 1);
                edges[p] = make_int2(cols[ee], __float_as_int(vals[ee]));
            }
        }
    }
}

// ---------------- fused layer: SpMM + dense transform ----------------
// Block = 256 threads (4 waves), 64 rows/block (16 rows/wave).
// Phase 1 (SpMM): wave gathers neighbor rows (4 edge slots x 16 lanes x float4),
//   accumulates row of t1e, writes A1s[m][k] = t1e, A2s[m][k] = emb*t1e (LDS, [m][k] layout).
// Phase 2 (dense): lane = output dim n; W row n held in 64 VGPRs, two passes (W1 then W2,
//   same registers). A reads are 16B LDS broadcasts (conflict-free).
template <int SPLIT>
__global__ __launch_bounds__(256) void k_layer(const int*  __restrict__ row_ptr,
                                               const int2* __restrict__ edges,
                                               const float* __restrict__ ebU,
                                               const float* __restrict__ ebI,
                                               float* __restrict__ emb_out,
                                               const float* __restrict__ W1,
                                               const float* __restrict__ b1,
                                               const float* __restrict__ W2,
                                               const float* __restrict__ b2) {
    __shared__ float A1s[64][68];
    __shared__ float A2s[64][68];

    int tid  = threadIdx.x;
    int wave = tid >> 6, lane = tid & 63;
    int slot = lane >> 4, sl = lane & 15;                // 4 edge slots x 16 dim-groups
    int mbase   = wave * 16;
    int rowbase = blockIdx.x * 64 + mbase;

    // ---- Phase 1: SpMM into LDS ----
    for (int r = 0; r < 16; r++) {
        int row = rowbase + r;
        if (row >= N_NODES) break;
        int s = row_ptr[row], e = row_ptr[row + 1];
        float4 acc = make_float4(0.f, 0.f, 0.f, 0.f);
        for (int p = s + slot; p < e; p += 4) {
            int2  ed = edges[p];
            int   c  = ed.x;
            float v  = __int_as_float(ed.y);
            const float* src;
            if (SPLIT) src = (c < N_USERS) ? (ebU + c * EMBED)
                                           : (ebI + (c - N_USERS) * EMBED);
            else       src = ebU + c * EMBED;
            float4 ev = *(const float4*)(src + 4 * sl);
            acc.x += v * ev.x; acc.y += v * ev.y; acc.z += v * ev.z; acc.w += v * ev.w;
        }
        acc.x += __shfl_xor(acc.x, 16); acc.y += __shfl_xor(acc.y, 16);
        acc.z += __shfl_xor(acc.z, 16); acc.w += __shfl_xor(acc.w, 16);
        acc.x += __shfl_xor(acc.x, 32); acc.y += __shfl_xor(acc.y, 32);
        acc.z += __shfl_xor(acc.z, 32); acc.w += __shfl_xor(acc.w, 32);
        if (slot == 0) {
            const float* own;
            if (SPLIT) own = (row < N_USERS) ? (ebU + row * EMBED)
                                             : (ebI + (row - N_USERS) * EMBED);
            else       own = ebU + row * EMBED;
            float4 e4 = *(const float4*)(own + 4 * sl);
            *(float4*)&A1s[mbase + r][4 * sl] = acc;
            float4 p4 = make_float4(acc.x * e4.x, acc.y * e4.y, acc.z * e4.z, acc.w * e4.w);
            *(float4*)&A2s[mbase + r][4 * sl] = p4;
        }
    }
    __syncthreads();

    // ---- Phase 2: dense outer-product, lane = output dim n ----
    float bsum = b1[lane] + b2[lane];
    float o[16];
#pragma unroll
    for (int r = 0; r < 16; r++) o[r] = bsum;

#pragma unroll 1
    for (int pass = 0; pass < 2; pass++) {
        const float* Wm = pass ? W2 : W1;
        float wr[64];
#pragma unroll
        for (int q = 0; q < 16; q++) {
            float4 w4 = *(const float4*)&Wm[lane * 64 + 4 * q];
            wr[4 * q] = w4.x; wr[4 * q + 1] = w4.y; wr[4 * q + 2] = w4.z; wr[4 * q + 3] = w4.w;
        }
#pragma unroll
        for (int r = 0; r < 16; r++) {
            const float* Ar = pass ? A2s[mbase + r] : A1s[mbase + r];
            float s0 = 0.f, s1 = 0.f, s2 = 0.f, s3 = 0.f;
#pragma unroll
            for (int q = 0; q < 16; q += 4) {
                float4 a0 = *(const float4*)&Ar[4 * q];
                float4 a1 = *(const float4*)&Ar[4 * q + 4];
                float4 a2 = *(const float4*)&Ar[4 * q + 8];
                float4 a3 = *(const float4*)&Ar[4 * q + 12];
                s0 += a0.x * wr[4*q+0]  + a0.y * wr[4*q+1]  + a0.z * wr[4*q+2]  + a0.w * wr[4*q+3];
                s1 += a1.x * wr[4*q+4]  + a1.y * wr[4*q+5]  + a1.z * wr[4*q+6]  + a1.w * wr[4*q+7];
                s2 += a2.x * wr[4*q+8]  + a2.y * wr[4*q+9]  + a2.z * wr[4*q+10] + a2.w * wr[4*q+11];
                s3 += a3.x * wr[4*q+12] + a3.y * wr[4*q+13] + a3.z * wr[4*q+14] + a3.w * wr[4*q+15];
            }
            o[r] += (s0 + s1) + (s2 + s3);
        }
    }

    // ---- epilogue: leaky relu + coalesced store (256B per row) ----
#pragma unroll
    for (int r = 0; r < 16; r++) {
        int row = rowbase + r;
        if (row < N_NODES) {
            float v = o[r];
            v = (v > 0.f) ? v : 0.01f * v;
            emb_out[row * EMBED + lane] = v;
        }
    }
}

// ---------------- scoring ----------------
__global__ __launch_bounds__(256) void k_score0(const float* __restrict__ ue,
                                                const float* __restrict__ ie,
                                                const int* __restrict__ u,
                                                const int* __restrict__ ii,
                                                const int* __restrict__ jj,
                                                float* __restrict__ posAcc,
                                                float* __restrict__ negAcc) {
    int wave = threadIdx.x >> 6, lane = threadIdx.x & 63;
    int b = blockIdx.x * 4 + wave;                       // grid = 2048 exact
    float eu = ue[u[b]  * EMBED + lane];
    float ep = ie[ii[b] * EMBED + lane];
    float en = ie[jj[b] * EMBED + lane];
    float p = eu * ep, n = eu * en;
    for (int o = 1; o < 64; o <<= 1) {
        p += __shfl_xor(p, o);
        n += __shfl_xor(n, o);
    }
    if (lane == 0) {
        posAcc[b] += p;
        negAcc[b] += n;
    }
}

__global__ __launch_bounds__(256) void k_score1(const float* __restrict__ emb,
                                                const int* __restrict__ u,
                                                const int* __restrict__ ii,
                                                const int* __restrict__ jj,
                                                float* __restrict__ posAcc,
                                                float* __restrict__ negAcc) {
    int wave = threadIdx.x >> 6, lane = threadIdx.x & 63;
    int b = blockIdx.x * 4 + wave;                       // grid = 2048 exact
    int ru = u[b];
    int ri = N_USERS + ii[b];
    int rj = N_USERS + jj[b];
    float eu = emb[ru * EMBED + lane];
    float ep = emb[ri * EMBED + lane];
    float en = emb[rj * EMBED + lane];
    float su = eu * eu, sp = ep * ep, sn = en * en;
    for (int o = 1; o < 64; o <<= 1) {
        su += __shfl_xor(su, o);
        sp += __shfl_xor(sp, o);
        sn += __shfl_xor(sn, o);
    }
    eu /= fmaxf(sqrtf(su), 1e-12f);
    ep /= fmaxf(sqrtf(sp), 1e-12f);
    en /= fmaxf(sqrtf(sn), 1e-12f);
    float p = eu * ep, n = eu * en;
    for (int o = 1; o < 64; o <<= 1) {
        p += __shfl_xor(p, o);
        n += __shfl_xor(n, o);
    }
    if (lane == 0) {
        posAcc[b] += p;
        negAcc[b] += n;
    }
}

// ---------------- final loss ----------------
__global__ __launch_bounds__(256) void k_loss(const float* __restrict__ pa,
                                              const float* __restrict__ na,
                                              float* __restrict__ out) {
    int b = blockIdx.x * 256 + threadIdx.x;              // grid = 32 exact
    float z = pa[b] - na[b];
    float x = -z;
    float sp = fmaxf(x, 0.f) + log1pf(expf(-fabsf(x)));  // softplus(-z)
    for (int o = 1; o < 64; o <<= 1) sp += __shfl_xor(sp, o);
    __shared__ float s[4];
    int wave = threadIdx.x >> 6, lane = threadIdx.x & 63;
    if (lane == 0) s[wave] = sp;
    __syncthreads();
    if (threadIdx.x == 0) {
        float t = s[0] + s[1] + s[2] + s[3];
        atomicAdd(out, t * (1.f / (float)BATCH));
    }
}

extern "C" void kernel_launch(void* const* d_in, const int* in_sizes, int n_in,
                              void* d_out, int out_size, void* d_ws, size_t ws_size,
                              hipStream_t stream) {
    const float* user_emb = (const float*)d_in[0];
    const float* item_emb = (const float*)d_in[1];
    const float* W1       = (const float*)d_in[2];
    const float* b1       = (const float*)d_in[3];
    const float* W2       = (const float*)d_in[4];
    const float* b2       = (const float*)d_in[5];
    const float* adj_vals = (const float*)d_in[6];
    const int*   adj_rows = (const int*)d_in[7];
    const int*   adj_cols = (const int*)d_in[8];
    const int*   u_idx    = (const int*)d_in[9];
    const int*   i_idx    = (const int*)d_in[10];
    const int*   j_idx    = (const int*)d_in[11];
    float* out = (float*)d_out;

    // workspace layout (bytes) — <= 94,065,664 B (same footprint as before)
    char* ws = (char*)d_ws;
    float* embA    = (float*)(ws);                                  // 38,400,000
    float* embB    = (float*)(ws + 38400000);                       // 38,400,000
    int*   row_ptr = (int*)  (ws + 76800000);                       // 600,064
    int*   cursor  = (int*)  (ws + 77400064);                       // 600,064
    int2*  edges   = (int2*) (ws + 78000128);                       // 16,000,000
    float* posAcc  = (float*)(ws + 94000128);                       // 32,768
    float* negAcc  = (float*)(ws + 94032896);                       // 32,768
    // scan scratch lives in the (not-yet-written) embB region
    int*   partials = (int*)(ws + 38400000);
    int*   blkoff   = (int*)(ws + 38400000 + 4096);

    hipMemsetAsync(cursor, 0, N_NODES * sizeof(int), stream);
    hipMemsetAsync(posAcc, 0, 2 * BATCH * sizeof(float), stream);
    hipMemsetAsync(d_out, 0, sizeof(float), stream);

    // CSR build (hierarchical scan, packed int2 edges)
    k_count<<<(N_EDGES / 4 + 255) / 256, 256, 0, stream>>>(adj_rows, cursor);
    k_scan_partial<<<SCAN_NBLK, 256, 0, stream>>>(cursor, partials);
    k_scan_blk<<<1, 256, 0, stream>>>(partials, blkoff);
    k_scan_apply<<<SCAN_NBLK, 256, 0, stream>>>(cursor, blkoff, row_ptr, cursor);
    k_scatter<<<(N_EDGES / 4 + 255) / 256, 256, 0, stream>>>(adj_rows, adj_cols, adj_vals,
                                                             cursor, edges);

    // layer-0 scoring on raw (unnormalized, un-concatenated) embeddings
    k_score0<<<BATCH / 4, 256, 0, stream>>>(user_emb, item_emb, u_idx, i_idx, j_idx,
                                            posAcc, negAcc);

    const int LGRID = (N_NODES + 63) / 64;  // 2344

    // layer 0: reads split inputs, writes embA
    k_layer<1><<<LGRID, 256, 0, stream>>>(row_ptr, edges, user_emb, item_emb, embA,
                                          W1, b1, W2, b2);
    k_score1<<<BATCH / 4, 256, 0, stream>>>(embA, u_idx, i_idx, j_idx, posAcc, negAcc);

    // layer 1: embA -> embB
    k_layer<0><<<LGRID, 256, 0, stream>>>(row_ptr, edges, embA, embA, embB,
                                          W1 + 4096, b1 + 64, W2 + 4096, b2 + 64);
    k_score1<<<BATCH / 4, 256, 0, stream>>>(embB, u_idx, i_idx, j_idx, posAcc, negAcc);

    // layer 2: embB -> embA
    k_layer<0><<<LGRID, 256, 0, stream>>>(row_ptr, edges, embB, embB, embA,
                                          W1 + 8192, b1 + 128, W2 + 8192, b2 + 128);
    k_score1<<<BATCH / 4, 256, 0, stream>>>(embA, u_idx, i_idx, j_idx, posAcc, negAcc);

    k_loss<<<BATCH / 256, 256, 0, stream>>>(posAcc, negAcc, out);
}

// Round 5
// 590.664 us; speedup vs baseline: 2.0092x; 2.0092x over previous
//
#include <hip/hip_runtime.h>
#include <hip/hip_bf16.h>
#include <math.h>

#define N_USERS 50000
#define N_ITEMS 100000
#define N_NODES 150000
#define N_EDGES 2000000
#define EMBED 64
#define N_LAYERS 3
#define BATCH 8192

#define SCAN_CHUNK 1024
#define SCAN_NBLK ((N_NODES + SCAN_CHUNK - 1) / SCAN_CHUNK)  // 147

__device__ __forceinline__ float bf2f(unsigned short u) {
    union { unsigned int i; float f; } c; c.i = ((unsigned int)u) << 16; return c.f;
}
__device__ __forceinline__ unsigned short f2bf(float f) {
    __hip_bfloat16 h = __float2bfloat16(f);               // RNE
    union { __hip_bfloat16 h; unsigned short u; } c; c.h = h; return c.u;
}

// ---------------- build unified bf16 table from split f32 inputs ----------------
__global__ __launch_bounds__(256) void k_tobf16(const float4* __restrict__ ue,
                                                const float4* __restrict__ ie,
                                                ushort4* __restrict__ tab) {
    int idx = blockIdx.x * 256 + threadIdx.x;             // float4 index
    const int TOT = N_NODES * EMBED / 4;                  // 2,400,000
    const int UPART = N_USERS * EMBED / 4;                // 800,000
    if (idx < TOT) {
        float4 v = (idx < UPART) ? ue[idx] : ie[idx - UPART];
        ushort4 o;
        o.x = f2bf(v.x); o.y = f2bf(v.y); o.z = f2bf(v.z); o.w = f2bf(v.w);
        tab[idx] = o;
    }
}

// ---------------- CSR build ----------------
__global__ __launch_bounds__(256) void k_count(const int* __restrict__ rows, int* __restrict__ cnt) {
    int e = (blockIdx.x * 256 + threadIdx.x) * 4;
    if (e + 3 < N_EDGES) {
        int4 r = *(const int4*)&rows[e];
        atomicAdd(&cnt[r.x], 1);
        atomicAdd(&cnt[r.y], 1);
        atomicAdd(&cnt[r.z], 1);
        atomicAdd(&cnt[r.w], 1);
    } else {
        for (int k = 0; k < 4; k++)
            if (e + k < N_EDGES) atomicAdd(&cnt[rows[e + k]], 1);
    }
}

__global__ __launch_bounds__(256) void k_scan_partial(const int* __restrict__ cnt,
                                                      int* __restrict__ partials) {
    int base = blockIdx.x * SCAN_CHUNK + threadIdx.x * 4;
    int v = 0;
    if (base + 3 < N_NODES) {
        int4 c = *(const int4*)&cnt[base];
        v = c.x + c.y + c.z + c.w;
    } else {
        for (int k = 0; k < 4; k++)
            if (base + k < N_NODES) v += cnt[base + k];
    }
    for (int o = 1; o < 64; o <<= 1) v += __shfl_xor(v, o);
    __shared__ int s[4];
    int wid = threadIdx.x >> 6, lane = threadIdx.x & 63;
    if (lane == 0) s[wid] = v;
    __syncthreads();
    if (threadIdx.x == 0) partials[blockIdx.x] = s[0] + s[1] + s[2] + s[3];
}

__global__ __launch_bounds__(256) void k_scan_blk(const int* __restrict__ partials,
                                                  int* __restrict__ blkoff) {
    int tid = threadIdx.x;
    int x = (tid < SCAN_NBLK) ? partials[tid] : 0;
    int v = x;
    int lane = tid & 63, wid = tid >> 6;
    for (int o = 1; o < 64; o <<= 1) {
        int t = __shfl_up(v, o);
        if (lane >= o) v += t;
    }
    __shared__ int ws[4];
    if (lane == 63) ws[wid] = v;
    __syncthreads();
    int add = 0;
    for (int w = 0; w < wid; w++) add += ws[w];
    if (tid < SCAN_NBLK) blkoff[tid] = add + v - x;      // exclusive prefix
}

__global__ __launch_bounds__(256) void k_scan_apply(const int* __restrict__ cnt,
                                                    const int* __restrict__ blkoff,
                                                    int* __restrict__ row_ptr,
                                                    int* __restrict__ cursor) {
    int tid = threadIdx.x;
    int base = blockIdx.x * SCAN_CHUNK + tid * 4;
    int c0 = 0, c1 = 0, c2 = 0, c3 = 0;
    if (base + 3 < N_NODES) {
        int4 c = *(const int4*)&cnt[base];
        c0 = c.x; c1 = c.y; c2 = c.z; c3 = c.w;
    } else {
        if (base     < N_NODES) c0 = cnt[base];
        if (base + 1 < N_NODES) c1 = cnt[base + 1];
        if (base + 2 < N_NODES) c2 = cnt[base + 2];
        if (base + 3 < N_NODES) c3 = cnt[base + 3];
    }
    int tsum = c0 + c1 + c2 + c3;
    int lane = tid & 63, wid = tid >> 6;
    int v = tsum;
    for (int o = 1; o < 64; o <<= 1) {
        int t = __shfl_up(v, o);
        if (lane >= o) v += t;
    }
    __shared__ int ws[4];
    if (lane == 63) ws[wid] = v;
    __syncthreads();
    int add = blkoff[blockIdx.x];
    for (int w = 0; w < wid; w++) add += ws[w];
    int excl = add + v - tsum;
    int p0 = excl, p1 = p0 + c0, p2 = p1 + c1, p3 = p2 + c2;
    if (base + 3 < N_NODES) {
        int4 rp = make_int4(p0, p1, p2, p3);
        *(int4*)&row_ptr[base] = rp;
        *(int4*)&cursor[base]  = rp;
    } else {
        int ps[4] = {p0, p1, p2, p3};
        for (int k = 0; k < 4; k++)
            if (base + k < N_NODES) { row_ptr[base + k] = ps[k]; cursor[base + k] = ps[k]; }
    }
    if (base < N_NODES && base + 4 >= N_NODES) {
        row_ptr[N_NODES] = p3 + c3;                      // total edge count
    }
}

// scatter edges as packed (col, val) int2 — one scattered cache line per edge
__global__ __launch_bounds__(256) void k_scatter(const int* __restrict__ rows,
                                                 const int* __restrict__ cols,
                                                 const float* __restrict__ vals,
                                                 int* __restrict__ cursor,
                                                 int2* __restrict__ edges) {
    int e = (blockIdx.x * 256 + threadIdx.x) * 4;
    if (e + 3 < N_EDGES) {
        int4   r = *(const int4*)&rows[e];
        int4   c = *(const int4*)&cols[e];
        float4 v = *(const float4*)&vals[e];
        int p;
        p = atomicAdd(&cursor[r.x], 1); edges[p] = make_int2(c.x, __float_as_int(v.x));
        p = atomicAdd(&cursor[r.y], 1); edges[p] = make_int2(c.y, __float_as_int(v.y));
        p = atomicAdd(&cursor[r.z], 1); edges[p] = make_int2(c.z, __float_as_int(v.z));
        p = atomicAdd(&cursor[r.w], 1); edges[p] = make_int2(c.w, __float_as_int(v.w));
    } else {
        for (int k = 0; k < 4; k++) {
            int ee = e + k;
            if (ee < N_EDGES) {
                int r = rows[ee];
                int p = atomicAdd(&cursor[r], 1);
                edges[p] = make_int2(cols[ee], __float_as_int(vals[ee]));
            }
        }
    }
}

// ---------------- SpMM: t1e = A @ embH (bf16 table, wave per row, 8 edge slots) ----------------
__global__ __launch_bounds__(256) void k_spmm(const int*  __restrict__ row_ptr,
                                              const int2* __restrict__ edges,
                                              const unsigned short* __restrict__ tab,
                                              float* __restrict__ t1e) {
    int wave = threadIdx.x >> 6, lane = threadIdx.x & 63;
    int row = blockIdx.x * 4 + wave;                     // grid = 37500 exact
    int slot = lane >> 3;                                // 0..7 : edge slot
    int sl   = lane & 7;                                 // dims 8*sl .. 8*sl+7
    int s = row_ptr[row], e = row_ptr[row + 1];
    float acc[8] = {};
    for (int p = s + slot; p < e; p += 8) {
        int2  ed = edges[p];
        int   c  = ed.x;
        float v  = __int_as_float(ed.y);
        uint4 w  = *(const uint4*)&tab[c * EMBED + 8 * sl];
        union { unsigned int i; float f; } cv;
        cv.i = w.x << 16;          acc[0] += v * cv.f;
        cv.i = w.x & 0xffff0000u;  acc[1] += v * cv.f;
        cv.i = w.y << 16;          acc[2] += v * cv.f;
        cv.i = w.y & 0xffff0000u;  acc[3] += v * cv.f;
        cv.i = w.z << 16;          acc[4] += v * cv.f;
        cv.i = w.z & 0xffff0000u;  acc[5] += v * cv.f;
        cv.i = w.w << 16;          acc[6] += v * cv.f;
        cv.i = w.w & 0xffff0000u;  acc[7] += v * cv.f;
    }
    // combine the 8 edge slots (lanes sl, sl+8, ..., sl+56)
#pragma unroll
    for (int k = 0; k < 8; k++) {
        acc[k] += __shfl_xor(acc[k], 8);
        acc[k] += __shfl_xor(acc[k], 16);
        acc[k] += __shfl_xor(acc[k], 32);
    }
    if (slot == 0) {
        float4 lo = make_float4(acc[0], acc[1], acc[2], acc[3]);
        float4 hi = make_float4(acc[4], acc[5], acc[6], acc[7]);
        *(float4*)&t1e[row * EMBED + 8 * sl]     = lo;
        *(float4*)&t1e[row * EMBED + 8 * sl + 4] = hi;
    }
}

// ---------------- dense: embH_out = bf16(leaky_relu(t1e@W1^T+b1 + (embH_in*t1e)@W2^T+b2)) ---
// Register-tiled GEMM: block = 256 threads, M-tile 64, K = 64, 4x4 outputs/thread.
__global__ __launch_bounds__(256) void k_dense(const float* __restrict__ t1e,
                                               const unsigned short* __restrict__ embH_in,
                                               unsigned short* __restrict__ embH_out,
                                               const float* __restrict__ W1,
                                               const float* __restrict__ b1,
                                               const float* __restrict__ W2,
                                               const float* __restrict__ b2) {
    __shared__ float A1s[64][68];   // [k][m] = t1e[row0+m][k]
    __shared__ float A2s[64][68];   // [k][m] = emb[row0+m][k] * t1e[row0+m][k]
    __shared__ float B1s[64][68];   // [k][n] = W1[n][k]
    __shared__ float B2s[64][68];   // [k][n] = W2[n][k]
    __shared__ float bs[64];        // b1[n] + b2[n]

    int tid  = threadIdx.x;
    int row0 = blockIdx.x * 64;

    // --- fill B tiles (transpose W1/W2) + bias ---
    {
        int f0 = tid * 16;                               // 4096 floats / 256 threads
#pragma unroll
        for (int q = 0; q < 4; q++) {
            int f = f0 + q * 4;
            int n = f >> 6, k = f & 63;
            float4 w1 = *(const float4*)&W1[f];
            float4 w2 = *(const float4*)&W2[f];
            B1s[k + 0][n] = w1.x; B1s[k + 1][n] = w1.y; B1s[k + 2][n] = w1.z; B1s[k + 3][n] = w1.w;
            B2s[k + 0][n] = w2.x; B2s[k + 1][n] = w2.y; B2s[k + 2][n] = w2.z; B2s[k + 3][n] = w2.w;
        }
        if (tid < 64) bs[tid] = b1[tid] + b2[tid];
    }

    // --- fill A tiles ---
    {
        int r   = tid >> 2;                              // 0..63
        int row = row0 + r;
        bool ok = row < N_NODES;
#pragma unroll
        for (int q = 0; q < 4; q++) {
            int c = ((tid & 3) * 4 + q) * 4;             // k base
            float4 t = make_float4(0.f, 0.f, 0.f, 0.f);
            float e0 = 0.f, e1 = 0.f, e2 = 0.f, e3 = 0.f;
            if (ok) {
                t = *(const float4*)&t1e[row * EMBED + c];
                uint2 w = *(const uint2*)&embH_in[row * EMBED + c];
                union { unsigned int i; float f; } cv;
                cv.i = w.x << 16;         e0 = cv.f;
                cv.i = w.x & 0xffff0000u; e1 = cv.f;
                cv.i = w.y << 16;         e2 = cv.f;
                cv.i = w.y & 0xffff0000u; e3 = cv.f;
            }
            A1s[c + 0][r] = t.x;      A1s[c + 1][r] = t.y;
            A1s[c + 2][r] = t.z;      A1s[c + 3][r] = t.w;
            A2s[c + 0][r] = t.x * e0; A2s[c + 1][r] = t.y * e1;
            A2s[c + 2][r] = t.z * e2; A2s[c + 3][r] = t.w * e3;
        }
    }
    __syncthreads();

    int tr = tid >> 4, tc = tid & 15;
    int m0 = tr * 4, n0 = tc * 4;
    float acc[4][4] = {};

#pragma unroll 8
    for (int k = 0; k < 64; k++) {
        float4 a1v = *(const float4*)&A1s[k][m0];
        float4 a2v = *(const float4*)&A2s[k][m0];
        float4 b1v = *(const float4*)&B1s[k][n0];
        float4 b2v = *(const float4*)&B2s[k][n0];
        float a1[4] = {a1v.x, a1v.y, a1v.z, a1v.w};
        float a2[4] = {a2v.x, a2v.y, a2v.z, a2v.w};
        float bb1[4] = {b1v.x, b1v.y, b1v.z, b1v.w};
        float bb2[4] = {b2v.x, b2v.y, b2v.z, b2v.w};
#pragma unroll
        for (int i = 0; i < 4; i++)
#pragma unroll
            for (int j = 0; j < 4; j++)
                acc[i][j] += a1[i] * bb1[j] + a2[i] * bb2[j];
    }

    // --- epilogue: bias + leaky relu + bf16 store ---
    float bias[4] = {bs[n0], bs[n0 + 1], bs[n0 + 2], bs[n0 + 3]};
#pragma unroll
    for (int i = 0; i < 4; i++) {
        int row = row0 + m0 + i;
        if (row < N_NODES) {
            ushort4 o;
            float v0 = acc[i][0] + bias[0]; v0 = (v0 > 0.f) ? v0 : 0.01f * v0;
            float v1 = acc[i][1] + bias[1]; v1 = (v1 > 0.f) ? v1 : 0.01f * v1;
            float v2 = acc[i][2] + bias[2]; v2 = (v2 > 0.f) ? v2 : 0.01f * v2;
            float v3 = acc[i][3] + bias[3]; v3 = (v3 > 0.f) ? v3 : 0.01f * v3;
            o.x = f2bf(v0); o.y = f2bf(v1); o.z = f2bf(v2); o.w = f2bf(v3);
            *(ushort4*)&embH_out[row * EMBED + n0] = o;
        }
    }
}

// ---------------- scoring ----------------
__global__ __launch_bounds__(256) void k_score0(const float* __restrict__ ue,
                                                const float* __restrict__ ie,
                                                const int* __restrict__ u,
                                                const int* __restrict__ ii,
                                                const int* __restrict__ jj,
                                                float* __restrict__ posAcc,
                                                float* __restrict__ negAcc) {
    int wave = threadIdx.x >> 6, lane = threadIdx.x & 63;
    int b = blockIdx.x * 4 + wave;                       // grid = 2048 exact
    float eu = ue[u[b]  * EMBED + lane];
    float ep = ie[ii[b] * EMBED + lane];
    float en = ie[jj[b] * EMBED + lane];
    float p = eu * ep, n = eu * en;
    for (int o = 1; o < 64; o <<= 1) {
        p += __shfl_xor(p, o);
        n += __shfl_xor(n, o);
    }
    if (lane == 0) {
        posAcc[b] += p;
        negAcc[b] += n;
    }
}

__global__ __launch_bounds__(256) void k_score1(const unsigned short* __restrict__ tab,
                                                const int* __restrict__ u,
                                                const int* __restrict__ ii,
                                                const int* __restrict__ jj,
                                                float* __restrict__ posAcc,
                                                float* __restrict__ negAcc) {
    int wave = threadIdx.x >> 6, lane = threadIdx.x & 63;
    int b = blockIdx.x * 4 + wave;                       // grid = 2048 exact
    int ru = u[b];
    int ri = N_USERS + ii[b];
    int rj = N_USERS + jj[b];
    float eu = bf2f(tab[ru * EMBED + lane]);
    float ep = bf2f(tab[ri * EMBED + lane]);
    float en = bf2f(tab[rj * EMBED + lane]);
    float su = eu * eu, sp = ep * ep, sn = en * en;
    for (int o = 1; o < 64; o <<= 1) {
        su += __shfl_xor(su, o);
        sp += __shfl_xor(sp, o);
        sn += __shfl_xor(sn, o);
    }
    eu /= fmaxf(sqrtf(su), 1e-12f);
    ep /= fmaxf(sqrtf(sp), 1e-12f);
    en /= fmaxf(sqrtf(sn), 1e-12f);
    float p = eu * ep, n = eu * en;
    for (int o = 1; o < 64; o <<= 1) {
        p += __shfl_xor(p, o);
        n += __shfl_xor(n, o);
    }
    if (lane == 0) {
        posAcc[b] += p;
        negAcc[b] += n;
    }
}

// ---------------- final loss ----------------
__global__ __launch_bounds__(256) void k_loss(const float* __restrict__ pa,
                                              const float* __restrict__ na,
                                              float* __restrict__ out) {
    int b = blockIdx.x * 256 + threadIdx.x;              // grid = 32 exact
    float z = pa[b] - na[b];
    float x = -z;
    float sp = fmaxf(x, 0.f) + log1pf(expf(-fabsf(x)));  // softplus(-z)
    for (int o = 1; o < 64; o <<= 1) sp += __shfl_xor(sp, o);
    __shared__ float s[4];
    int wave = threadIdx.x >> 6, lane = threadIdx.x & 63;
    if (lane == 0) s[wave] = sp;
    __syncthreads();
    if (threadIdx.x == 0) {
        float t = s[0] + s[1] + s[2] + s[3];
        atomicAdd(out, t * (1.f / (float)BATCH));
    }
}

extern "C" void kernel_launch(void* const* d_in, const int* in_sizes, int n_in,
                              void* d_out, int out_size, void* d_ws, size_t ws_size,
                              hipStream_t stream) {
    const float* user_emb = (const float*)d_in[0];
    const float* item_emb = (const float*)d_in[1];
    const float* W1       = (const float*)d_in[2];
    const float* b1       = (const float*)d_in[3];
    const float* W2       = (const float*)d_in[4];
    const float* b2       = (const float*)d_in[5];
    const float* adj_vals = (const float*)d_in[6];
    const int*   adj_rows = (const int*)d_in[7];
    const int*   adj_cols = (const int*)d_in[8];
    const int*   u_idx    = (const int*)d_in[9];
    const int*   i_idx    = (const int*)d_in[10];
    const int*   j_idx    = (const int*)d_in[11];
    float* out = (float*)d_out;

    // workspace layout (bytes) — 94,065,664 total (same as validated footprint)
    char* ws = (char*)d_ws;
    float*          t1e     = (float*)(ws);                           // 38,400,000
    unsigned short* HA      = (unsigned short*)(ws + 38400000);       // 19,200,000
    unsigned short* HB      = (unsigned short*)(ws + 57600000);       // 19,200,000
    int*            row_ptr = (int*)(ws + 76800000);                  // 600,064
    int*            cursor  = (int*)(ws + 77400064);                  // 600,064
    int2*           edges   = (int2*)(ws + 78000128);                 // 16,000,000
    float*          posAcc  = (float*)(ws + 94000128);                // 32,768
    float*          negAcc  = (float*)(ws + 94032896);                // 32,768
    // scan scratch lives in the (not-yet-written) t1e region
    int* partials = (int*)(ws);
    int* blkoff   = (int*)(ws + 4096);

    hipMemsetAsync(cursor, 0, N_NODES * sizeof(int), stream);
    hipMemsetAsync(posAcc, 0, 2 * BATCH * sizeof(float), stream);
    hipMemsetAsync(d_out, 0, sizeof(float), stream);

    // bf16 gather table from split inputs (also serves as the concat)
    k_tobf16<<<(N_NODES * EMBED / 4 + 255) / 256, 256, 0, stream>>>(
        (const float4*)user_emb, (const float4*)item_emb, (ushort4*)HA);

    // CSR build (hierarchical scan, packed int2 edges)
    k_count<<<(N_EDGES / 4 + 255) / 256, 256, 0, stream>>>(adj_rows, cursor);
    k_scan_partial<<<SCAN_NBLK, 256, 0, stream>>>(cursor, partials);
    k_scan_blk<<<1, 256, 0, stream>>>(partials, blkoff);
    k_scan_apply<<<SCAN_NBLK, 256, 0, stream>>>(cursor, blkoff, row_ptr, cursor);
    k_scatter<<<(N_EDGES / 4 + 255) / 256, 256, 0, stream>>>(adj_rows, adj_cols, adj_vals,
                                                             cursor, edges);

    // layer-0 scoring on raw f32 inputs (exact)
    k_score0<<<BATCH / 4, 256, 0, stream>>>(user_emb, item_emb, u_idx, i_idx, j_idx,
                                            posAcc, negAcc);

    const int SGRID = N_NODES / 4;        // 37500 (wave per row)
    const int DGRID = (N_NODES + 63) / 64;

    // layer 0: HA -> t1e -> HB
    k_spmm<<<SGRID, 256, 0, stream>>>(row_ptr, edges, HA, t1e);
    k_dense<<<DGRID, 256, 0, stream>>>(t1e, HA, HB, W1, b1, W2, b2);
    k_score1<<<BATCH / 4, 256, 0, stream>>>(HB, u_idx, i_idx, j_idx, posAcc, negAcc);

    // layer 1: HB -> t1e -> HA
    k_spmm<<<SGRID, 256, 0, stream>>>(row_ptr, edges, HB, t1e);
    k_dense<<<DGRID, 256, 0, stream>>>(t1e, HB, HA, W1 + 4096, b1 + 64, W2 + 4096, b2 + 64);
    k_score1<<<BATCH / 4, 256, 0, stream>>>(HA, u_idx, i_idx, j_idx, posAcc, negAcc);

    // layer 2: HA -> t1e -> HB
    k_spmm<<<SGRID, 256, 0, stream>>>(row_ptr, edges, HA, t1e);
    k_dense<<<DGRID, 256, 0, stream>>>(t1e, HA, HB, W1 + 8192, b1 + 128, W2 + 8192, b2 + 128);
    k_score1<<<BATCH / 4, 256, 0, stream>>>(HB, u_idx, i_idx, j_idx, posAcc, negAcc);

    k_loss<<<BATCH / 256, 256, 0, stream>>>(posAcc, negAcc, out);
}

// Round 6
// 527.372 us; speedup vs baseline: 2.2504x; 1.1200x over previous
//
#include <hip/hip_runtime.h>
#include <hip/hip_bf16.h>
#include <math.h>

#define N_USERS 50000
#define N_ITEMS 100000
#define N_NODES 150000
#define N_EDGES 2000000
#define EMBED 64
#define N_LAYERS 3
#define BATCH 8192

#define SCAN_CHUNK 1024
#define SCAN_NBLK ((N_NODES + SCAN_CHUNK - 1) / SCAN_CHUNK)  // 147
#define NBKT SCAN_NBLK                                       // 147 buckets (row>>10)
#define EPB 4096                                             // edges per phase-A block

__device__ __forceinline__ float bf2f(unsigned short u) {
    union { unsigned int i; float f; } c; c.i = ((unsigned int)u) << 16; return c.f;
}
__device__ __forceinline__ unsigned short f2bf(float f) {
    __hip_bfloat16 h = __float2bfloat16(f);               // RNE
    union { __hip_bfloat16 h; unsigned short u; } c; c.h = h; return c.u;
}

// ---------------- build unified bf16 table from split f32 inputs ----------------
__global__ __launch_bounds__(256) void k_tobf16(const float4* __restrict__ ue,
                                                const float4* __restrict__ ie,
                                                ushort4* __restrict__ tab) {
    int idx = blockIdx.x * 256 + threadIdx.x;             // float4 index
    const int TOT = N_NODES * EMBED / 4;                  // 2,400,000
    const int UPART = N_USERS * EMBED / 4;                // 800,000
    if (idx < TOT) {
        float4 v = (idx < UPART) ? ue[idx] : ie[idx - UPART];
        ushort4 o;
        o.x = f2bf(v.x); o.y = f2bf(v.y); o.z = f2bf(v.z); o.w = f2bf(v.w);
        tab[idx] = o;
    }
}

// ---------------- CSR build ----------------
__global__ __launch_bounds__(256) void k_count(const int* __restrict__ rows, int* __restrict__ cnt) {
    int e = (blockIdx.x * 256 + threadIdx.x) * 4;
    if (e + 3 < N_EDGES) {
        int4 r = *(const int4*)&rows[e];
        atomicAdd(&cnt[r.x], 1);
        atomicAdd(&cnt[r.y], 1);
        atomicAdd(&cnt[r.z], 1);
        atomicAdd(&cnt[r.w], 1);
    } else {
        for (int k = 0; k < 4; k++)
            if (e + k < N_EDGES) atomicAdd(&cnt[rows[e + k]], 1);
    }
}

__global__ __launch_bounds__(256) void k_scan_partial(const int* __restrict__ cnt,
                                                      int* __restrict__ partials) {
    int base = blockIdx.x * SCAN_CHUNK + threadIdx.x * 4;
    int v = 0;
    if (base + 3 < N_NODES) {
        int4 c = *(const int4*)&cnt[base];
        v = c.x + c.y + c.z + c.w;
    } else {
        for (int k = 0; k < 4; k++)
            if (base + k < N_NODES) v += cnt[base + k];
    }
    for (int o = 1; o < 64; o <<= 1) v += __shfl_xor(v, o);
    __shared__ int s[4];
    int wid = threadIdx.x >> 6, lane = threadIdx.x & 63;
    if (lane == 0) s[wid] = v;
    __syncthreads();
    if (threadIdx.x == 0) partials[blockIdx.x] = s[0] + s[1] + s[2] + s[3];
}

__global__ __launch_bounds__(256) void k_scan_blk(const int* __restrict__ partials,
                                                  int* __restrict__ blkoff) {
    int tid = threadIdx.x;
    int x = (tid < SCAN_NBLK) ? partials[tid] : 0;
    int v = x;
    int lane = tid & 63, wid = tid >> 6;
    for (int o = 1; o < 64; o <<= 1) {
        int t = __shfl_up(v, o);
        if (lane >= o) v += t;
    }
    __shared__ int ws[4];
    if (lane == 63) ws[wid] = v;
    __syncthreads();
    int add = 0;
    for (int w = 0; w < wid; w++) add += ws[w];
    if (tid < SCAN_NBLK) blkoff[tid] = add + v - x;      // exclusive prefix
}

__global__ __launch_bounds__(256) void k_scan_apply(const int* __restrict__ cnt,
                                                    const int* __restrict__ blkoff,
                                                    int* __restrict__ row_ptr,
                                                    int* __restrict__ cursor) {
    int tid = threadIdx.x;
    int base = blockIdx.x * SCAN_CHUNK + tid * 4;
    int c0 = 0, c1 = 0, c2 = 0, c3 = 0;
    if (base + 3 < N_NODES) {
        int4 c = *(const int4*)&cnt[base];
        c0 = c.x; c1 = c.y; c2 = c.z; c3 = c.w;
    } else {
        if (base     < N_NODES) c0 = cnt[base];
        if (base + 1 < N_NODES) c1 = cnt[base + 1];
        if (base + 2 < N_NODES) c2 = cnt[base + 2];
        if (base + 3 < N_NODES) c3 = cnt[base + 3];
    }
    int tsum = c0 + c1 + c2 + c3;
    int lane = tid & 63, wid = tid >> 6;
    int v = tsum;
    for (int o = 1; o < 64; o <<= 1) {
        int t = __shfl_up(v, o);
        if (lane >= o) v += t;
    }
    __shared__ int ws[4];
    if (lane == 63) ws[wid] = v;
    __syncthreads();
    int add = blkoff[blockIdx.x];
    for (int w = 0; w < wid; w++) add += ws[w];
    int excl = add + v - tsum;
    int p0 = excl, p1 = p0 + c0, p2 = p1 + c1, p3 = p2 + c2;
    if (base + 3 < N_NODES) {
        int4 rp = make_int4(p0, p1, p2, p3);
        *(int4*)&row_ptr[base] = rp;
        *(int4*)&cursor[base]  = rp;
    } else {
        int ps[4] = {p0, p1, p2, p3};
        for (int k = 0; k < 4; k++)
            if (base + k < N_NODES) { row_ptr[base + k] = ps[k]; cursor[base + k] = ps[k]; }
    }
    if (base < N_NODES && base + 4 >= N_NODES) {
        row_ptr[N_NODES] = p3 + c3;                      // total edge count
    }
}

__global__ __launch_bounds__(256) void k_init_bkt(const int* __restrict__ row_ptr,
                                                  int* __restrict__ bkt_cursor) {
    int t = threadIdx.x;
    if (t < NBKT) bkt_cursor[t] = row_ptr[t << 10];
}

// Phase A: bucket edges by row>>10 into bucket-contiguous scratch (dense chunked writes)
__global__ __launch_bounds__(256) void k_bucketA(const int* __restrict__ rows,
                                                 const int* __restrict__ cols,
                                                 const float* __restrict__ vals,
                                                 int* __restrict__ bkt_cursor,
                                                 int4* __restrict__ bucketed) {
    __shared__ int sr[EPB];
    __shared__ int sc[EPB];
    __shared__ int sv[EPB];
    __shared__ int hist[152];
    __shared__ int cbase[152];
    int tid = threadIdx.x;
    int e0 = blockIdx.x * EPB;
    int cnt = N_EDGES - e0; if (cnt > EPB) cnt = EPB;

    for (int i = tid; i < cnt; i += 256) {
        sr[i] = rows[e0 + i];
        sc[i] = cols[e0 + i];
        sv[i] = __float_as_int(vals[e0 + i]);
    }
    if (tid < 152) hist[tid] = 0;
    __syncthreads();
    for (int i = tid; i < cnt; i += 256) atomicAdd(&hist[sr[i] >> 10], 1);
    __syncthreads();
    if (tid < NBKT) cbase[tid] = atomicAdd(&bkt_cursor[tid], hist[tid]);
    __syncthreads();
    if (tid < 152) hist[tid] = 0;
    __syncthreads();
    for (int i = tid; i < cnt; i += 256) {
        int b = sr[i] >> 10;
        int off = atomicAdd(&hist[b], 1);
        bucketed[cbase[b] + off] = make_int4(sr[i], sc[i], sv[i], 0);
    }
}

// Phase B: within each bucket, scatter to final CSR slot (writes stay in one ~110KB window)
__global__ __launch_bounds__(1024) void k_bucketB(const int* __restrict__ row_ptr,
                                                  const int4* __restrict__ bucketed,
                                                  int* __restrict__ cursor,
                                                  int2* __restrict__ edges) {
    int b = blockIdx.x;
    int s = row_ptr[b << 10];
    int endrow = (b + 1) << 10; if (endrow > N_NODES) endrow = N_NODES;
    int e = row_ptr[endrow];
    for (int p = s + threadIdx.x; p < e; p += 1024) {
        int4 ed = bucketed[p];
        int pos = atomicAdd(&cursor[ed.x], 1);
        edges[pos] = make_int2(ed.y, ed.z);
    }
}

// ---------------- SpMM: t1eH = A @ embH (bf16 in, bf16 out, wave per row, 8 edge slots) ----
__global__ __launch_bounds__(256) void k_spmm(const int*  __restrict__ row_ptr,
                                              const int2* __restrict__ edges,
                                              const unsigned short* __restrict__ tab,
                                              unsigned short* __restrict__ t1eH) {
    int wave = threadIdx.x >> 6, lane = threadIdx.x & 63;
    int row = blockIdx.x * 4 + wave;                     // grid = 37500 exact
    int slot = lane >> 3;                                // 0..7 : edge slot
    int sl   = lane & 7;                                 // dims 8*sl .. 8*sl+7
    int s = row_ptr[row], e = row_ptr[row + 1];
    float acc[8] = {};
    for (int p = s + slot; p < e; p += 8) {
        int2  ed = edges[p];
        int   c  = ed.x;
        float v  = __int_as_float(ed.y);
        uint4 w  = *(const uint4*)&tab[c * EMBED + 8 * sl];
        union { unsigned int i; float f; } cv;
        cv.i = w.x << 16;          acc[0] += v * cv.f;
        cv.i = w.x & 0xffff0000u;  acc[1] += v * cv.f;
        cv.i = w.y << 16;          acc[2] += v * cv.f;
        cv.i = w.y & 0xffff0000u;  acc[3] += v * cv.f;
        cv.i = w.z << 16;          acc[4] += v * cv.f;
        cv.i = w.z & 0xffff0000u;  acc[5] += v * cv.f;
        cv.i = w.w << 16;          acc[6] += v * cv.f;
        cv.i = w.w & 0xffff0000u;  acc[7] += v * cv.f;
    }
#pragma unroll
    for (int k = 0; k < 8; k++) {
        acc[k] += __shfl_xor(acc[k], 8);
        acc[k] += __shfl_xor(acc[k], 16);
        acc[k] += __shfl_xor(acc[k], 32);
    }
    if (slot == 0) {
        uint4 o;
        o.x = (unsigned)f2bf(acc[0]) | ((unsigned)f2bf(acc[1]) << 16);
        o.y = (unsigned)f2bf(acc[2]) | ((unsigned)f2bf(acc[3]) << 16);
        o.z = (unsigned)f2bf(acc[4]) | ((unsigned)f2bf(acc[5]) << 16);
        o.w = (unsigned)f2bf(acc[6]) | ((unsigned)f2bf(acc[7]) << 16);
        *(uint4*)&t1eH[row * EMBED + 8 * sl] = o;
    }
}

// ---------------- dense: embH_out = bf16(leaky_relu(t1e@W1^T+b1 + (emb*t1e)@W2^T+b2)) ---
__global__ __launch_bounds__(256) void k_dense(const unsigned short* __restrict__ t1eH,
                                               const unsigned short* __restrict__ embH_in,
                                               unsigned short* __restrict__ embH_out,
                                               const float* __restrict__ W1,
                                               const float* __restrict__ b1,
                                               const float* __restrict__ W2,
                                               const float* __restrict__ b2) {
    __shared__ float A1s[64][68];   // [k][m] = t1e[row0+m][k]
    __shared__ float A2s[64][68];   // [k][m] = emb[row0+m][k] * t1e[row0+m][k]
    __shared__ float B1s[64][68];   // [k][n] = W1[n][k]
    __shared__ float B2s[64][68];   // [k][n] = W2[n][k]
    __shared__ float bs[64];        // b1[n] + b2[n]

    int tid  = threadIdx.x;
    int row0 = blockIdx.x * 64;

    // --- fill B tiles (transpose W1/W2) + bias ---
    {
        int f0 = tid * 16;                               // 4096 floats / 256 threads
#pragma unroll
        for (int q = 0; q < 4; q++) {
            int f = f0 + q * 4;
            int n = f >> 6, k = f & 63;
            float4 w1 = *(const float4*)&W1[f];
            float4 w2 = *(const float4*)&W2[f];
            B1s[k + 0][n] = w1.x; B1s[k + 1][n] = w1.y; B1s[k + 2][n] = w1.z; B1s[k + 3][n] = w1.w;
            B2s[k + 0][n] = w2.x; B2s[k + 1][n] = w2.y; B2s[k + 2][n] = w2.z; B2s[k + 3][n] = w2.w;
        }
        if (tid < 64) bs[tid] = b1[tid] + b2[tid];
    }

    // --- fill A tiles (bf16 t1e, bf16 emb) ---
    {
        int r   = tid >> 2;                              // 0..63
        int row = row0 + r;
        bool ok = row < N_NODES;
#pragma unroll
        for (int q = 0; q < 4; q++) {
            int c = ((tid & 3) * 4 + q) * 4;             // k base
            float t0 = 0.f, t1 = 0.f, t2 = 0.f, t3 = 0.f;
            float e0 = 0.f, e1 = 0.f, e2 = 0.f, e3 = 0.f;
            if (ok) {
                uint2 tw = *(const uint2*)&t1eH[row * EMBED + c];
                uint2 ew = *(const uint2*)&embH_in[row * EMBED + c];
                union { unsigned int i; float f; } cv;
                cv.i = tw.x << 16;         t0 = cv.f;
                cv.i = tw.x & 0xffff0000u; t1 = cv.f;
                cv.i = tw.y << 16;         t2 = cv.f;
                cv.i = tw.y & 0xffff0000u; t3 = cv.f;
                cv.i = ew.x << 16;         e0 = cv.f;
                cv.i = ew.x & 0xffff0000u; e1 = cv.f;
                cv.i = ew.y << 16;         e2 = cv.f;
                cv.i = ew.y & 0xffff0000u; e3 = cv.f;
            }
            A1s[c + 0][r] = t0;      A1s[c + 1][r] = t1;
            A1s[c + 2][r] = t2;      A1s[c + 3][r] = t3;
            A2s[c + 0][r] = t0 * e0; A2s[c + 1][r] = t1 * e1;
            A2s[c + 2][r] = t2 * e2; A2s[c + 3][r] = t3 * e3;
        }
    }
    __syncthreads();

    int tr = tid >> 4, tc = tid & 15;
    int m0 = tr * 4, n0 = tc * 4;
    float acc[4][4] = {};

#pragma unroll 8
    for (int k = 0; k < 64; k++) {
        float4 a1v = *(const float4*)&A1s[k][m0];
        float4 a2v = *(const float4*)&A2s[k][m0];
        float4 b1v = *(const float4*)&B1s[k][n0];
        float4 b2v = *(const float4*)&B2s[k][n0];
        float a1[4] = {a1v.x, a1v.y, a1v.z, a1v.w};
        float a2[4] = {a2v.x, a2v.y, a2v.z, a2v.w};
        float bb1[4] = {b1v.x, b1v.y, b1v.z, b1v.w};
        float bb2[4] = {b2v.x, b2v.y, b2v.z, b2v.w};
#pragma unroll
        for (int i = 0; i < 4; i++)
#pragma unroll
            for (int j = 0; j < 4; j++)
                acc[i][j] += a1[i] * bb1[j] + a2[i] * bb2[j];
    }

    // --- epilogue: bias + leaky relu + bf16 store ---
    float bias[4] = {bs[n0], bs[n0 + 1], bs[n0 + 2], bs[n0 + 3]};
#pragma unroll
    for (int i = 0; i < 4; i++) {
        int row = row0 + m0 + i;
        if (row < N_NODES) {
            ushort4 o;
            float v0 = acc[i][0] + bias[0]; v0 = (v0 > 0.f) ? v0 : 0.01f * v0;
            float v1 = acc[i][1] + bias[1]; v1 = (v1 > 0.f) ? v1 : 0.01f * v1;
            float v2 = acc[i][2] + bias[2]; v2 = (v2 > 0.f) ? v2 : 0.01f * v2;
            float v3 = acc[i][3] + bias[3]; v3 = (v3 > 0.f) ? v3 : 0.01f * v3;
            o.x = f2bf(v0); o.y = f2bf(v1); o.z = f2bf(v2); o.w = f2bf(v3);
            *(ushort4*)&embH_out[row * EMBED + n0] = o;
        }
    }
}

// ---------------- scoring ----------------
__global__ __launch_bounds__(256) void k_score0(const float* __restrict__ ue,
                                                const float* __restrict__ ie,
                                                const int* __restrict__ u,
                                                const int* __restrict__ ii,
                                                const int* __restrict__ jj,
                                                float* __restrict__ posAcc,
                                                float* __restrict__ negAcc) {
    int wave = threadIdx.x >> 6, lane = threadIdx.x & 63;
    int b = blockIdx.x * 4 + wave;                       // grid = 2048 exact
    float eu = ue[u[b]  * EMBED + lane];
    float ep = ie[ii[b] * EMBED + lane];
    float en = ie[jj[b] * EMBED + lane];
    float p = eu * ep, n = eu * en;
    for (int o = 1; o < 64; o <<= 1) {
        p += __shfl_xor(p, o);
        n += __shfl_xor(n, o);
    }
    if (lane == 0) {
        posAcc[b] += p;
        negAcc[b] += n;
    }
}

__global__ __launch_bounds__(256) void k_score1(const unsigned short* __restrict__ tab,
                                                const int* __restrict__ u,
                                                const int* __restrict__ ii,
                                                const int* __restrict__ jj,
                                                float* __restrict__ posAcc,
                                                float* __restrict__ negAcc) {
    int wave = threadIdx.x >> 6, lane = threadIdx.x & 63;
    int b = blockIdx.x * 4 + wave;                       // grid = 2048 exact
    int ru = u[b];
    int ri = N_USERS + ii[b];
    int rj = N_USERS + jj[b];
    float eu = bf2f(tab[ru * EMBED + lane]);
    float ep = bf2f(tab[ri * EMBED + lane]);
    float en = bf2f(tab[rj * EMBED + lane]);
    float su = eu * eu, sp = ep * ep, sn = en * en;
    for (int o = 1; o < 64; o <<= 1) {
        su += __shfl_xor(su, o);
        sp += __shfl_xor(sp, o);
        sn += __shfl_xor(sn, o);
    }
    eu /= fmaxf(sqrtf(su), 1e-12f);
    ep /= fmaxf(sqrtf(sp), 1e-12f);
    en /= fmaxf(sqrtf(sn), 1e-12f);
    float p = eu * ep, n = eu * en;
    for (int o = 1; o < 64; o <<= 1) {
        p += __shfl_xor(p, o);
        n += __shfl_xor(n, o);
    }
    if (lane == 0) {
        posAcc[b] += p;
        negAcc[b] += n;
    }
}

// ---------------- final loss ----------------
__global__ __launch_bounds__(256) void k_loss(const float* __restrict__ pa,
                                              const float* __restrict__ na,
                                              float* __restrict__ out) {
    int b = blockIdx.x * 256 + threadIdx.x;              // grid = 32 exact
    float z = pa[b] - na[b];
    float x = -z;
    float sp = fmaxf(x, 0.f) + log1pf(expf(-fabsf(x)));  // softplus(-z)
    for (int o = 1; o < 64; o <<= 1) sp += __shfl_xor(sp, o);
    __shared__ float s[4];
    int wave = threadIdx.x >> 6, lane = threadIdx.x & 63;
    if (lane == 0) s[wave] = sp;
    __syncthreads();
    if (threadIdx.x == 0) {
        float t = s[0] + s[1] + s[2] + s[3];
        atomicAdd(out, t * (1.f / (float)BATCH));
    }
}

extern "C" void kernel_launch(void* const* d_in, const int* in_sizes, int n_in,
                              void* d_out, int out_size, void* d_ws, size_t ws_size,
                              hipStream_t stream) {
    const float* user_emb = (const float*)d_in[0];
    const float* item_emb = (const float*)d_in[1];
    const float* W1       = (const float*)d_in[2];
    const float* b1       = (const float*)d_in[3];
    const float* W2       = (const float*)d_in[4];
    const float* b2       = (const float*)d_in[5];
    const float* adj_vals = (const float*)d_in[6];
    const int*   adj_rows = (const int*)d_in[7];
    const int*   adj_cols = (const int*)d_in[8];
    const int*   u_idx    = (const int*)d_in[9];
    const int*   i_idx    = (const int*)d_in[10];
    const int*   j_idx    = (const int*)d_in[11];
    float* out = (float*)d_out;

    // workspace layout (bytes) — 94,065,664 total (validated footprint)
    // region [0, 38,400,000): time-shared:
    //   scan: partials @ +0, blkoff @ +4096            (dead after k_scan_apply)
    //   CSR:  bucketed int4[2M] @ +0 (32,000,000 B), bkt_cursor @ +32,000,000
    //   layers: t1eH bf16[150000*64] @ +0 (19,200,000) (written first by k_spmm)
    char* ws = (char*)d_ws;
    unsigned short* t1eH    = (unsigned short*)(ws);
    int*            partials = (int*)(ws);
    int*            blkoff   = (int*)(ws + 4096);
    int4*           bucketed = (int4*)(ws);
    int*            bkt_cursor = (int*)(ws + 32000000);
    unsigned short* HA      = (unsigned short*)(ws + 38400000);       // 19,200,000
    unsigned short* HB      = (unsigned short*)(ws + 57600000);       // 19,200,000
    int*            row_ptr = (int*)(ws + 76800000);                  // 600,064
    int*            cursor  = (int*)(ws + 77400064);                  // 600,064
    int2*           edges   = (int2*)(ws + 78000128);                 // 16,000,000
    float*          posAcc  = (float*)(ws + 94000128);                // 32,768
    float*          negAcc  = (float*)(ws + 94032896);                // 32,768

    hipMemsetAsync(cursor, 0, N_NODES * sizeof(int), stream);
    hipMemsetAsync(posAcc, 0, 2 * BATCH * sizeof(float), stream);
    hipMemsetAsync(d_out, 0, sizeof(float), stream);

    // bf16 gather table from split inputs (also serves as the concat)
    k_tobf16<<<(N_NODES * EMBED / 4 + 255) / 256, 256, 0, stream>>>(
        (const float4*)user_emb, (const float4*)item_emb, (ushort4*)HA);

    // CSR build: count -> scan -> bucketed two-phase scatter
    k_count<<<(N_EDGES / 4 + 255) / 256, 256, 0, stream>>>(adj_rows, cursor);
    k_scan_partial<<<SCAN_NBLK, 256, 0, stream>>>(cursor, partials);
    k_scan_blk<<<1, 256, 0, stream>>>(partials, blkoff);
    k_scan_apply<<<SCAN_NBLK, 256, 0, stream>>>(cursor, blkoff, row_ptr, cursor);
    k_init_bkt<<<1, 256, 0, stream>>>(row_ptr, bkt_cursor);
    k_bucketA<<<(N_EDGES + EPB - 1) / EPB, 256, 0, stream>>>(adj_rows, adj_cols, adj_vals,
                                                             bkt_cursor, bucketed);
    k_bucketB<<<NBKT, 1024, 0, stream>>>(row_ptr, bucketed, cursor, edges);

    // layer-0 scoring on raw f32 inputs (exact)
    k_score0<<<BATCH / 4, 256, 0, stream>>>(user_emb, item_emb, u_idx, i_idx, j_idx,
                                            posAcc, negAcc);

    const int SGRID = N_NODES / 4;        // 37500 (wave per row)
    const int DGRID = (N_NODES + 63) / 64;

    // layer 0: HA -> t1eH -> HB
    k_spmm<<<SGRID, 256, 0, stream>>>(row_ptr, edges, HA, t1eH);
    k_dense<<<DGRID, 256, 0, stream>>>(t1eH, HA, HB, W1, b1, W2, b2);
    k_score1<<<BATCH / 4, 256, 0, stream>>>(HB, u_idx, i_idx, j_idx, posAcc, negAcc);

    // layer 1: HB -> t1eH -> HA
    k_spmm<<<SGRID, 256, 0, stream>>>(row_ptr, edges, HB, t1eH);
    k_dense<<<DGRID, 256, 0, stream>>>(t1eH, HB, HA, W1 + 4096, b1 + 64, W2 + 4096, b2 + 64);
    k_score1<<<BATCH / 4, 256, 0, stream>>>(HA, u_idx, i_idx, j_idx, posAcc, negAcc);

    // layer 2: HA -> t1eH -> HB
    k_spmm<<<SGRID, 256, 0, stream>>>(row_ptr, edges, HA, t1eH);
    k_dense<<<DGRID, 256, 0, stream>>>(t1eH, HA, HB, W1 + 8192, b1 + 128, W2 + 8192, b2 + 128);
    k_score1<<<BATCH / 4, 256, 0, stream>>>(HB, u_idx, i_idx, j_idx, posAcc, negAcc);

    k_loss<<<BATCH / 256, 256, 0, stream>>>(posAcc, negAcc, out);
}

// Round 7
// 448.633 us; speedup vs baseline: 2.6453x; 1.1755x over previous
//
#include <hip/hip_runtime.h>
#include <hip/hip_bf16.h>
#include <math.h>

#define N_USERS 50000
#define N_ITEMS 100000
#define N_NODES 150000
#define N_EDGES 2000000
#define EMBED 64
#define N_LAYERS 3
#define BATCH 8192

#define BSHIFT 9
#define BROWS 512                                         // rows per bucket
#define NBKT ((N_NODES + BROWS - 1) / BROWS)              // 293
#define EPB 4096                                          // edges per phase-A block

__device__ __forceinline__ float bf2f(unsigned short u) {
    union { unsigned int i; float f; } c; c.i = ((unsigned int)u) << 16; return c.f;
}
__device__ __forceinline__ unsigned short f2bf(float f) {
    __hip_bfloat16 h = __float2bfloat16(f);               // RNE
    union { __hip_bfloat16 h; unsigned short u; } c; c.h = h; return c.u;
}

// ---------------- build unified bf16 table from split f32 inputs ----------------
__global__ __launch_bounds__(256) void k_tobf16(const float4* __restrict__ ue,
                                                const float4* __restrict__ ie,
                                                ushort4* __restrict__ tab) {
    int idx = blockIdx.x * 256 + threadIdx.x;             // float4 index
    const int TOT = N_NODES * EMBED / 4;                  // 2,400,000
    const int UPART = N_USERS * EMBED / 4;                // 800,000
    if (idx < TOT) {
        float4 v = (idx < UPART) ? ue[idx] : ie[idx - UPART];
        ushort4 o;
        o.x = f2bf(v.x); o.y = f2bf(v.y); o.z = f2bf(v.z); o.w = f2bf(v.w);
        tab[idx] = o;
    }
}

// ---------------- bucket-level histogram (LDS-aggregated; 293 counters) ----------------
__global__ __launch_bounds__(256) void k_bkt_count(const int* __restrict__ rows,
                                                   int* __restrict__ bkt_count) {
    __shared__ int hist[NBKT];
    int tid = threadIdx.x;
    for (int t = tid; t < NBKT; t += 256) hist[t] = 0;
    __syncthreads();
    int e = (blockIdx.x * 256 + tid) * 4;
    if (e + 3 < N_EDGES) {
        int4 r = *(const int4*)&rows[e];
        atomicAdd(&hist[r.x >> BSHIFT], 1);
        atomicAdd(&hist[r.y >> BSHIFT], 1);
        atomicAdd(&hist[r.z >> BSHIFT], 1);
        atomicAdd(&hist[r.w >> BSHIFT], 1);
    } else {
        for (int k = 0; k < 4; k++)
            if (e + k < N_EDGES) atomicAdd(&hist[rows[e + k] >> BSHIFT], 1);
    }
    __syncthreads();
    for (int t = tid; t < NBKT; t += 256)
        if (hist[t] > 0) atomicAdd(&bkt_count[t], hist[t]);
}

// ---------------- scan of 293 bucket counts (1 block, 512 threads) ----------------
__global__ __launch_bounds__(512) void k_bkt_scan(const int* __restrict__ bkt_count,
                                                  int* __restrict__ bkt_base,
                                                  int* __restrict__ bkt_cursor,
                                                  int* __restrict__ row_ptr) {
    int tid = threadIdx.x;
    int x = (tid < NBKT) ? bkt_count[tid] : 0;
    int lane = tid & 63, wid = tid >> 6;
    int v = x;
    for (int o = 1; o < 64; o <<= 1) {
        int t = __shfl_up(v, o);
        if (lane >= o) v += t;
    }
    __shared__ int wsum[8];
    if (lane == 63) wsum[wid] = v;
    __syncthreads();
    int add = 0;
    for (int w = 0; w < wid; w++) add += wsum[w];
    int incl = add + v;
    int excl = incl - x;
    if (tid < NBKT) {
        bkt_base[tid]   = excl;
        bkt_cursor[tid] = excl;
    }
    if (tid == NBKT - 1) {
        bkt_base[NBKT]    = incl;          // == N_EDGES
        row_ptr[N_NODES]  = incl;
    }
}

// ---------------- Phase A: bucket edges into bucket-contiguous scratch ----------------
__global__ __launch_bounds__(256) void k_bucketA(const int* __restrict__ rows,
                                                 const int* __restrict__ cols,
                                                 const float* __restrict__ vals,
                                                 int* __restrict__ bkt_cursor,
                                                 int4* __restrict__ bucketed) {
    __shared__ int sr[EPB];
    __shared__ int sc[EPB];
    __shared__ int sv[EPB];
    __shared__ int hist[NBKT];
    __shared__ int cbase[NBKT];
    int tid = threadIdx.x;
    int e0 = blockIdx.x * EPB;
    int cnt = N_EDGES - e0; if (cnt > EPB) cnt = EPB;

    for (int i = tid; i < cnt; i += 256) {
        sr[i] = rows[e0 + i];
        sc[i] = cols[e0 + i];
        sv[i] = __float_as_int(vals[e0 + i]);
    }
    for (int t = tid; t < NBKT; t += 256) hist[t] = 0;
    __syncthreads();
    for (int i = tid; i < cnt; i += 256) atomicAdd(&hist[sr[i] >> BSHIFT], 1);
    __syncthreads();
    for (int t = tid; t < NBKT; t += 256)
        cbase[t] = (hist[t] > 0) ? atomicAdd(&bkt_cursor[t], hist[t]) : 0;
    __syncthreads();
    for (int t = tid; t < NBKT; t += 256) hist[t] = 0;
    __syncthreads();
    for (int i = tid; i < cnt; i += 256) {
        int b = sr[i] >> BSHIFT;
        int off = atomicAdd(&hist[b], 1);
        bucketed[cbase[b] + off] = make_int4(sr[i], sc[i], sv[i], 0);
    }
}

// ---------------- Phase C: per-bucket row_ptr build + scatter (LDS atomics only) -------
__global__ __launch_bounds__(1024) void k_bucketC(const int* __restrict__ bkt_base,
                                                  const int4* __restrict__ bucketed,
                                                  int* __restrict__ row_ptr,
                                                  int2* __restrict__ edges) {
    __shared__ int hist[BROWS];
    __shared__ int ssum[BROWS];
    __shared__ int cur[BROWS];
    int b = blockIdx.x, tid = threadIdx.x;
    int base = bkt_base[b];
    int cnt  = bkt_base[b + 1] - base;
    int row0 = b << BSHIFT;

    if (tid < BROWS) hist[tid] = 0;
    __syncthreads();
    for (int i = tid; i < cnt; i += 1024)
        atomicAdd(&hist[bucketed[base + i].x - row0], 1);
    __syncthreads();
    int own = 0;
    if (tid < BROWS) { own = hist[tid]; ssum[tid] = own; }
    __syncthreads();
    for (int off = 1; off < BROWS; off <<= 1) {
        int t = 0;
        if (tid < BROWS && tid >= off) t = ssum[tid - off];
        __syncthreads();
        if (tid < BROWS) ssum[tid] += t;
        __syncthreads();
    }
    if (tid < BROWS) {
        int excl = ssum[tid] - own;
        int grow = row0 + tid;
        if (grow < N_NODES) row_ptr[grow] = base + excl;
        cur[tid] = excl;
    }
    __syncthreads();
    for (int i = tid; i < cnt; i += 1024) {
        int4 ed = bucketed[base + i];
        int lr  = ed.x - row0;
        int off = atomicAdd(&cur[lr], 1);
        edges[base + off] = make_int2(ed.y, ed.z);
    }
}

// ---------------- SpMM: t1eH = A @ embH (bf16 in, bf16 out, wave per row, 8 edge slots) ----
__global__ __launch_bounds__(256) void k_spmm(const int*  __restrict__ row_ptr,
                                              const int2* __restrict__ edges,
                                              const unsigned short* __restrict__ tab,
                                              unsigned short* __restrict__ t1eH) {
    int wave = threadIdx.x >> 6, lane = threadIdx.x & 63;
    int row = blockIdx.x * 4 + wave;                     // grid = 37500 exact
    int slot = lane >> 3;                                // 0..7 : edge slot
    int sl   = lane & 7;                                 // dims 8*sl .. 8*sl+7
    int s = row_ptr[row], e = row_ptr[row + 1];
    float acc[8] = {};
    for (int p = s + slot; p < e; p += 8) {
        int2  ed = edges[p];
        int   c  = ed.x;
        float v  = __int_as_float(ed.y);
        uint4 w  = *(const uint4*)&tab[c * EMBED + 8 * sl];
        union { unsigned int i; float f; } cv;
        cv.i = w.x << 16;          acc[0] += v * cv.f;
        cv.i = w.x & 0xffff0000u;  acc[1] += v * cv.f;
        cv.i = w.y << 16;          acc[2] += v * cv.f;
        cv.i = w.y & 0xffff0000u;  acc[3] += v * cv.f;
        cv.i = w.z << 16;          acc[4] += v * cv.f;
        cv.i = w.z & 0xffff0000u;  acc[5] += v * cv.f;
        cv.i = w.w << 16;          acc[6] += v * cv.f;
        cv.i = w.w & 0xffff0000u;  acc[7] += v * cv.f;
    }
#pragma unroll
    for (int k = 0; k < 8; k++) {
        acc[k] += __shfl_xor(acc[k], 8);
        acc[k] += __shfl_xor(acc[k], 16);
        acc[k] += __shfl_xor(acc[k], 32);
    }
    if (slot == 0) {
        uint4 o;
        o.x = (unsigned)f2bf(acc[0]) | ((unsigned)f2bf(acc[1]) << 16);
        o.y = (unsigned)f2bf(acc[2]) | ((unsigned)f2bf(acc[3]) << 16);
        o.z = (unsigned)f2bf(acc[4]) | ((unsigned)f2bf(acc[5]) << 16);
        o.w = (unsigned)f2bf(acc[6]) | ((unsigned)f2bf(acc[7]) << 16);
        *(uint4*)&t1eH[row * EMBED + 8 * sl] = o;
    }
}

// ---------------- dense: embH_out = bf16(leaky_relu(t1e@W1^T+b1 + (emb*t1e)@W2^T+b2)) ---
__global__ __launch_bounds__(256) void k_dense(const unsigned short* __restrict__ t1eH,
                                               const unsigned short* __restrict__ embH_in,
                                               unsigned short* __restrict__ embH_out,
                                               const float* __restrict__ W1,
                                               const float* __restrict__ b1,
                                               const float* __restrict__ W2,
                                               const float* __restrict__ b2) {
    __shared__ float A1s[64][68];   // [k][m] = t1e[row0+m][k]
    __shared__ float A2s[64][68];   // [k][m] = emb[row0+m][k] * t1e[row0+m][k]
    __shared__ float B1s[64][68];   // [k][n] = W1[n][k]
    __shared__ float B2s[64][68];   // [k][n] = W2[n][k]
    __shared__ float bs[64];        // b1[n] + b2[n]

    int tid  = threadIdx.x;
    int row0 = blockIdx.x * 64;

    // --- fill B tiles (transpose W1/W2) + bias ---
    {
        int f0 = tid * 16;                               // 4096 floats / 256 threads
#pragma unroll
        for (int q = 0; q < 4; q++) {
            int f = f0 + q * 4;
            int n = f >> 6, k = f & 63;
            float4 w1 = *(const float4*)&W1[f];
            float4 w2 = *(const float4*)&W2[f];
            B1s[k + 0][n] = w1.x; B1s[k + 1][n] = w1.y; B1s[k + 2][n] = w1.z; B1s[k + 3][n] = w1.w;
            B2s[k + 0][n] = w2.x; B2s[k + 1][n] = w2.y; B2s[k + 2][n] = w2.z; B2s[k + 3][n] = w2.w;
        }
        if (tid < 64) bs[tid] = b1[tid] + b2[tid];
    }

    // --- fill A tiles (bf16 t1e, bf16 emb) ---
    {
        int r   = tid >> 2;                              // 0..63
        int row = row0 + r;
        bool ok = row < N_NODES;
#pragma unroll
        for (int q = 0; q < 4; q++) {
            int c = ((tid & 3) * 4 + q) * 4;             // k base
            float t0 = 0.f, t1 = 0.f, t2 = 0.f, t3 = 0.f;
            float e0 = 0.f, e1 = 0.f, e2 = 0.f, e3 = 0.f;
            if (ok) {
                uint2 tw = *(const uint2*)&t1eH[row * EMBED + c];
                uint2 ew = *(const uint2*)&embH_in[row * EMBED + c];
                union { unsigned int i; float f; } cv;
                cv.i = tw.x << 16;         t0 = cv.f;
                cv.i = tw.x & 0xffff0000u; t1 = cv.f;
                cv.i = tw.y << 16;         t2 = cv.f;
                cv.i = tw.y & 0xffff0000u; t3 = cv.f;
                cv.i = ew.x << 16;         e0 = cv.f;
                cv.i = ew.x & 0xffff0000u; e1 = cv.f;
                cv.i = ew.y << 16;         e2 = cv.f;
                cv.i = ew.y & 0xffff0000u; e3 = cv.f;
            }
            A1s[c + 0][r] = t0;      A1s[c + 1][r] = t1;
            A1s[c + 2][r] = t2;      A1s[c + 3][r] = t3;
            A2s[c + 0][r] = t0 * e0; A2s[c + 1][r] = t1 * e1;
            A2s[c + 2][r] = t2 * e2; A2s[c + 3][r] = t3 * e3;
        }
    }
    __syncthreads();

    int tr = tid >> 4, tc = tid & 15;
    int m0 = tr * 4, n0 = tc * 4;
    float acc[4][4] = {};

#pragma unroll 8
    for (int k = 0; k < 64; k++) {
        float4 a1v = *(const float4*)&A1s[k][m0];
        float4 a2v = *(const float4*)&A2s[k][m0];
        float4 b1v = *(const float4*)&B1s[k][n0];
        float4 b2v = *(const float4*)&B2s[k][n0];
        float a1[4] = {a1v.x, a1v.y, a1v.z, a1v.w};
        float a2[4] = {a2v.x, a2v.y, a2v.z, a2v.w};
        float bb1[4] = {b1v.x, b1v.y, b1v.z, b1v.w};
        float bb2[4] = {b2v.x, b2v.y, b2v.z, b2v.w};
#pragma unroll
        for (int i = 0; i < 4; i++)
#pragma unroll
            for (int j = 0; j < 4; j++)
                acc[i][j] += a1[i] * bb1[j] + a2[i] * bb2[j];
    }

    // --- epilogue: bias + leaky relu + bf16 store ---
    float bias[4] = {bs[n0], bs[n0 + 1], bs[n0 + 2], bs[n0 + 3]};
#pragma unroll
    for (int i = 0; i < 4; i++) {
        int row = row0 + m0 + i;
        if (row < N_NODES) {
            ushort4 o;
            float v0 = acc[i][0] + bias[0]; v0 = (v0 > 0.f) ? v0 : 0.01f * v0;
            float v1 = acc[i][1] + bias[1]; v1 = (v1 > 0.f) ? v1 : 0.01f * v1;
            float v2 = acc[i][2] + bias[2]; v2 = (v2 > 0.f) ? v2 : 0.01f * v2;
            float v3 = acc[i][3] + bias[3]; v3 = (v3 > 0.f) ? v3 : 0.01f * v3;
            o.x = f2bf(v0); o.y = f2bf(v1); o.z = f2bf(v2); o.w = f2bf(v3);
            *(ushort4*)&embH_out[row * EMBED + n0] = o;
        }
    }
}

// ---------------- scoring ----------------
__global__ __launch_bounds__(256) void k_score0(const float* __restrict__ ue,
                                                const float* __restrict__ ie,
                                                const int* __restrict__ u,
                                                const int* __restrict__ ii,
                                                const int* __restrict__ jj,
                                                float* __restrict__ posAcc,
                                                float* __restrict__ negAcc) {
    int wave = threadIdx.x >> 6, lane = threadIdx.x & 63;
    int b = blockIdx.x * 4 + wave;                       // grid = 2048 exact
    float eu = ue[u[b]  * EMBED + lane];
    float ep = ie[ii[b] * EMBED + lane];
    float en = ie[jj[b] * EMBED + lane];
    float p = eu * ep, n = eu * en;
    for (int o = 1; o < 64; o <<= 1) {
        p += __shfl_xor(p, o);
        n += __shfl_xor(n, o);
    }
    if (lane == 0) {
        posAcc[b] += p;
        negAcc[b] += n;
    }
}

__global__ __launch_bounds__(256) void k_score1(const unsigned short* __restrict__ tab,
                                                const int* __restrict__ u,
                                                const int* __restrict__ ii,
                                                const int* __restrict__ jj,
                                                float* __restrict__ posAcc,
                                                float* __restrict__ negAcc) {
    int wave = threadIdx.x >> 6, lane = threadIdx.x & 63;
    int b = blockIdx.x * 4 + wave;                       // grid = 2048 exact
    int ru = u[b];
    int ri = N_USERS + ii[b];
    int rj = N_USERS + jj[b];
    float eu = bf2f(tab[ru * EMBED + lane]);
    float ep = bf2f(tab[ri * EMBED + lane]);
    float en = bf2f(tab[rj * EMBED + lane]);
    float su = eu * eu, sp = ep * ep, sn = en * en;
    for (int o = 1; o < 64; o <<= 1) {
        su += __shfl_xor(su, o);
        sp += __shfl_xor(sp, o);
        sn += __shfl_xor(sn, o);
    }
    eu /= fmaxf(sqrtf(su), 1e-12f);
    ep /= fmaxf(sqrtf(sp), 1e-12f);
    en /= fmaxf(sqrtf(sn), 1e-12f);
    float p = eu * ep, n = eu * en;
    for (int o = 1; o < 64; o <<= 1) {
        p += __shfl_xor(p, o);
        n += __shfl_xor(n, o);
    }
    if (lane == 0) {
        posAcc[b] += p;
        negAcc[b] += n;
    }
}

// ---------------- final loss ----------------
__global__ __launch_bounds__(256) void k_loss(const float* __restrict__ pa,
                                              const float* __restrict__ na,
                                              float* __restrict__ out) {
    int b = blockIdx.x * 256 + threadIdx.x;              // grid = 32 exact
    float z = pa[b] - na[b];
    float x = -z;
    float sp = fmaxf(x, 0.f) + log1pf(expf(-fabsf(x)));  // softplus(-z)
    for (int o = 1; o < 64; o <<= 1) sp += __shfl_xor(sp, o);
    __shared__ float s[4];
    int wave = threadIdx.x >> 6, lane = threadIdx.x & 63;
    if (lane == 0) s[wave] = sp;
    __syncthreads();
    if (threadIdx.x == 0) {
        float t = s[0] + s[1] + s[2] + s[3];
        atomicAdd(out, t * (1.f / (float)BATCH));
    }
}

extern "C" void kernel_launch(void* const* d_in, const int* in_sizes, int n_in,
                              void* d_out, int out_size, void* d_ws, size_t ws_size,
                              hipStream_t stream) {
    const float* user_emb = (const float*)d_in[0];
    const float* item_emb = (const float*)d_in[1];
    const float* W1       = (const float*)d_in[2];
    const float* b1       = (const float*)d_in[3];
    const float* W2       = (const float*)d_in[4];
    const float* b2       = (const float*)d_in[5];
    const float* adj_vals = (const float*)d_in[6];
    const int*   adj_rows = (const int*)d_in[7];
    const int*   adj_cols = (const int*)d_in[8];
    const int*   u_idx    = (const int*)d_in[9];
    const int*   i_idx    = (const int*)d_in[10];
    const int*   j_idx    = (const int*)d_in[11];
    float* out = (float*)d_out;

    // workspace layout (bytes) — 94,065,664 total (validated footprint)
    // region [0, 38,400,000): time-shared:
    //   CSR:  bucketed int4[2M] @ +0 (32,000,000), bkt_count/base/cursor @ +32,000,000..
    //   layers: t1eH bf16[150000*64] @ +0 (19,200,000) (written first by k_spmm)
    char* ws = (char*)d_ws;
    unsigned short* t1eH       = (unsigned short*)(ws);
    int4*           bucketed   = (int4*)(ws);
    int*            bkt_count  = (int*)(ws + 32000000);               // 293 ints
    int*            bkt_base   = (int*)(ws + 32004096);               // 294 ints
    int*            bkt_cursor = (int*)(ws + 32008192);               // 293 ints
    unsigned short* HA         = (unsigned short*)(ws + 38400000);    // 19,200,000
    unsigned short* HB         = (unsigned short*)(ws + 57600000);    // 19,200,000
    int*            row_ptr    = (int*)(ws + 76800000);               // 600,004
    int2*           edges      = (int2*)(ws + 78000128);              // 16,000,000
    float*          posAcc     = (float*)(ws + 94000128);             // 32,768
    float*          negAcc     = (float*)(ws + 94032896);             // 32,768

    hipMemsetAsync(bkt_count, 0, 4096, stream);
    hipMemsetAsync(posAcc, 0, 2 * BATCH * sizeof(float), stream);
    hipMemsetAsync(d_out, 0, sizeof(float), stream);

    // bf16 gather table from split inputs (also serves as the concat)
    k_tobf16<<<(N_NODES * EMBED / 4 + 255) / 256, 256, 0, stream>>>(
        (const float4*)user_emb, (const float4*)item_emb, (ushort4*)HA);

    // CSR build: bucket count -> bucket scan -> chunked bucket scatter -> per-bucket sort
    k_bkt_count<<<(N_EDGES / 4 + 255) / 256, 256, 0, stream>>>(adj_rows, bkt_count);
    k_bkt_scan<<<1, 512, 0, stream>>>(bkt_count, bkt_base, bkt_cursor, row_ptr);
    k_bucketA<<<(N_EDGES + EPB - 1) / EPB, 256, 0, stream>>>(adj_rows, adj_cols, adj_vals,
                                                             bkt_cursor, bucketed);
    k_bucketC<<<NBKT, 1024, 0, stream>>>(bkt_base, bucketed, row_ptr, edges);

    // layer-0 scoring on raw f32 inputs (exact)
    k_score0<<<BATCH / 4, 256, 0, stream>>>(user_emb, item_emb, u_idx, i_idx, j_idx,
                                            posAcc, negAcc);

    const int SGRID = N_NODES / 4;        // 37500 (wave per row)
    const int DGRID = (N_NODES + 63) / 64;

    // layer 0: HA -> t1eH -> HB
    k_spmm<<<SGRID, 256, 0, stream>>>(row_ptr, edges, HA, t1eH);
    k_dense<<<DGRID, 256, 0, stream>>>(t1eH, HA, HB, W1, b1, W2, b2);
    k_score1<<<BATCH / 4, 256, 0, stream>>>(HB, u_idx, i_idx, j_idx, posAcc, negAcc);

    // layer 1: HB -> t1eH -> HA
    k_spmm<<<SGRID, 256, 0, stream>>>(row_ptr, edges, HB, t1eH);
    k_dense<<<DGRID, 256, 0, stream>>>(t1eH, HB, HA, W1 + 4096, b1 + 64, W2 + 4096, b2 + 64);
    k_score1<<<BATCH / 4, 256, 0, stream>>>(HA, u_idx, i_idx, j_idx, posAcc, negAcc);

    // layer 2: HA -> t1eH -> HB
    k_spmm<<<SGRID, 256, 0, stream>>>(row_ptr, edges, HA, t1eH);
    k_dense<<<DGRID, 256, 0, stream>>>(t1eH, HA, HB, W1 + 8192, b1 + 128, W2 + 8192, b2 + 128);
    k_score1<<<BATCH / 4, 256, 0, stream>>>(HB, u_idx, i_idx, j_idx, posAcc, negAcc);

    k_loss<<<BATCH / 256, 256, 0, stream>>>(posAcc, negAcc, out);
}

// Round 8
// 425.280 us; speedup vs baseline: 2.7906x; 1.0549x over previous
//
#include <hip/hip_runtime.h>
#include <hip/hip_bf16.h>
#include <math.h>

#define N_USERS 50000
#define N_ITEMS 100000
#define N_NODES 150000
#define N_EDGES 2000000
#define EMBED 64
#define N_LAYERS 3
#define BATCH 8192

#define BSHIFT 9
#define BROWS 512                                         // rows per bucket
#define NBKT ((N_NODES + BROWS - 1) / BROWS)              // 293
#define EPB 4096                                          // edges per phase-A block

typedef __bf16 bf16x8 __attribute__((ext_vector_type(8)));
typedef float  f32x4  __attribute__((ext_vector_type(4)));

__device__ __forceinline__ float bf2f(unsigned short u) {
    union { unsigned int i; float f; } c; c.i = ((unsigned int)u) << 16; return c.f;
}
__device__ __forceinline__ unsigned short f2bf(float f) {
    __hip_bfloat16 h = __float2bfloat16(f);               // RNE
    union { __hip_bfloat16 h; unsigned short u; } c; c.h = h; return c.u;
}
__device__ __forceinline__ bf16x8 as_bf8(uint4 u) {
    union { uint4 u; bf16x8 v; } c; c.u = u; return c.v;
}
__device__ __forceinline__ void unpack8(uint4 u, float* f) {
    union { unsigned int i; float x; } c;
    c.i = u.x << 16; f[0] = c.x; c.i = u.x & 0xffff0000u; f[1] = c.x;
    c.i = u.y << 16; f[2] = c.x; c.i = u.y & 0xffff0000u; f[3] = c.x;
    c.i = u.z << 16; f[4] = c.x; c.i = u.z & 0xffff0000u; f[5] = c.x;
    c.i = u.w << 16; f[6] = c.x; c.i = u.w & 0xffff0000u; f[7] = c.x;
}
__device__ __forceinline__ bf16x8 pack8(const float* f) {
    union { unsigned short s[8]; bf16x8 v; } u;
#pragma unroll
    for (int j = 0; j < 8; j++) u.s[j] = f2bf(f[j]);
    return u.v;
}

// ---------------- build unified bf16 table from split f32 inputs ----------------
__global__ __launch_bounds__(256) void k_tobf16(const float4* __restrict__ ue,
                                                const float4* __restrict__ ie,
                                                ushort4* __restrict__ tab) {
    int idx = blockIdx.x * 256 + threadIdx.x;             // float4 index
    const int TOT = N_NODES * EMBED / 4;                  // 2,400,000
    const int UPART = N_USERS * EMBED / 4;                // 800,000
    if (idx < TOT) {
        float4 v = (idx < UPART) ? ue[idx] : ie[idx - UPART];
        ushort4 o;
        o.x = f2bf(v.x); o.y = f2bf(v.y); o.z = f2bf(v.z); o.w = f2bf(v.w);
        tab[idx] = o;
    }
}

// ---------------- pack [W1;W2] into bf16 Wb[l][n][k0..127] + bias sums ----------------
__global__ __launch_bounds__(256) void k_wprep(const float* __restrict__ W1,
                                               const float* __restrict__ b1,
                                               const float* __restrict__ W2,
                                               const float* __restrict__ b2,
                                               unsigned short* __restrict__ Wb,
                                               float* __restrict__ bsum) {
    int idx = blockIdx.x * 256 + threadIdx.x;
    if (idx < 3 * 64 * 128) {
        int l = idx >> 13, rem = idx & 8191;
        int n = rem >> 7, k = rem & 127;
        float w = (k < 64) ? W1[l * 4096 + n * 64 + k] : W2[l * 4096 + n * 64 + (k - 64)];
        Wb[idx] = f2bf(w);
    } else if (idx < 3 * 64 * 128 + 192) {
        int t = idx - 3 * 64 * 128;
        bsum[t] = b1[t] + b2[t];
    }
}

// ---------------- bucket-level histogram (LDS-aggregated; 293 counters) ----------------
__global__ __launch_bounds__(256) void k_bkt_count(const int* __restrict__ rows,
                                                   int* __restrict__ bkt_count) {
    __shared__ int hist[NBKT];
    int tid = threadIdx.x;
    for (int t = tid; t < NBKT; t += 256) hist[t] = 0;
    __syncthreads();
    int e = (blockIdx.x * 256 + tid) * 4;
    if (e + 3 < N_EDGES) {
        int4 r = *(const int4*)&rows[e];
        atomicAdd(&hist[r.x >> BSHIFT], 1);
        atomicAdd(&hist[r.y >> BSHIFT], 1);
        atomicAdd(&hist[r.z >> BSHIFT], 1);
        atomicAdd(&hist[r.w >> BSHIFT], 1);
    } else {
        for (int k = 0; k < 4; k++)
            if (e + k < N_EDGES) atomicAdd(&hist[rows[e + k] >> BSHIFT], 1);
    }
    __syncthreads();
    for (int t = tid; t < NBKT; t += 256)
        if (hist[t] > 0) atomicAdd(&bkt_count[t], hist[t]);
}

// ---------------- scan of 293 bucket counts (1 block, 512 threads) ----------------
__global__ __launch_bounds__(512) void k_bkt_scan(const int* __restrict__ bkt_count,
                                                  int* __restrict__ bkt_base,
                                                  int* __restrict__ bkt_cursor,
                                                  int* __restrict__ row_ptr) {
    int tid = threadIdx.x;
    int x = (tid < NBKT) ? bkt_count[tid] : 0;
    int lane = tid & 63, wid = tid >> 6;
    int v = x;
    for (int o = 1; o < 64; o <<= 1) {
        int t = __shfl_up(v, o);
        if (lane >= o) v += t;
    }
    __shared__ int wsum[8];
    if (lane == 63) wsum[wid] = v;
    __syncthreads();
    int add = 0;
    for (int w = 0; w < wid; w++) add += wsum[w];
    int incl = add + v;
    int excl = incl - x;
    if (tid < NBKT) {
        bkt_base[tid]   = excl;
        bkt_cursor[tid] = excl;
    }
    if (tid == NBKT - 1) {
        bkt_base[NBKT]    = incl;          // == N_EDGES
        row_ptr[N_NODES]  = incl;
    }
}

// ---------------- Phase A: bucket edges into bucket-contiguous scratch ----------------
__global__ __launch_bounds__(256) void k_bucketA(const int* __restrict__ rows,
                                                 const int* __restrict__ cols,
                                                 const float* __restrict__ vals,
                                                 int* __restrict__ bkt_cursor,
                                                 int4* __restrict__ bucketed) {
    __shared__ int sr[EPB];
    __shared__ int sc[EPB];
    __shared__ int sv[EPB];
    __shared__ int hist[NBKT];
    __shared__ int cbase[NBKT];
    int tid = threadIdx.x;
    int e0 = blockIdx.x * EPB;
    int cnt = N_EDGES - e0; if (cnt > EPB) cnt = EPB;

    for (int i = tid; i < cnt; i += 256) {
        sr[i] = rows[e0 + i];
        sc[i] = cols[e0 + i];
        sv[i] = __float_as_int(vals[e0 + i]);
    }
    for (int t = tid; t < NBKT; t += 256) hist[t] = 0;
    __syncthreads();
    for (int i = tid; i < cnt; i += 256) atomicAdd(&hist[sr[i] >> BSHIFT], 1);
    __syncthreads();
    for (int t = tid; t < NBKT; t += 256)
        cbase[t] = (hist[t] > 0) ? atomicAdd(&bkt_cursor[t], hist[t]) : 0;
    __syncthreads();
    for (int t = tid; t < NBKT; t += 256) hist[t] = 0;
    __syncthreads();
    for (int i = tid; i < cnt; i += 256) {
        int b = sr[i] >> BSHIFT;
        int off = atomicAdd(&hist[b], 1);
        bucketed[cbase[b] + off] = make_int4(sr[i], sc[i], sv[i], 0);
    }
}

// ---------------- Phase C: per-bucket row_ptr build + scatter (LDS atomics only) -------
__global__ __launch_bounds__(1024) void k_bucketC(const int* __restrict__ bkt_base,
                                                  const int4* __restrict__ bucketed,
                                                  int* __restrict__ row_ptr,
                                                  int2* __restrict__ edges) {
    __shared__ int hist[BROWS];
    __shared__ int ssum[BROWS];
    __shared__ int cur[BROWS];
    int b = blockIdx.x, tid = threadIdx.x;
    int base = bkt_base[b];
    int cnt  = bkt_base[b + 1] - base;
    int row0 = b << BSHIFT;

    if (tid < BROWS) hist[tid] = 0;
    __syncthreads();
    for (int i = tid; i < cnt; i += 1024)
        atomicAdd(&hist[bucketed[base + i].x - row0], 1);
    __syncthreads();
    int own = 0;
    if (tid < BROWS) { own = hist[tid]; ssum[tid] = own; }
    __syncthreads();
    for (int off = 1; off < BROWS; off <<= 1) {
        int t = 0;
        if (tid < BROWS && tid >= off) t = ssum[tid - off];
        __syncthreads();
        if (tid < BROWS) ssum[tid] += t;
        __syncthreads();
    }
    if (tid < BROWS) {
        int excl = ssum[tid] - own;
        int grow = row0 + tid;
        if (grow < N_NODES) row_ptr[grow] = base + excl;
        cur[tid] = excl;
    }
    __syncthreads();
    for (int i = tid; i < cnt; i += 1024) {
        int4 ed = bucketed[base + i];
        int lr  = ed.x - row0;
        int off = atomicAdd(&cur[lr], 1);
        edges[base + off] = make_int2(ed.y, ed.z);
    }
}

// ---------------- SpMM: t1eH = A @ embH (bf16 in, bf16 out, wave per row, 8 edge slots) ----
__global__ __launch_bounds__(256) void k_spmm(const int*  __restrict__ row_ptr,
                                              const int2* __restrict__ edges,
                                              const unsigned short* __restrict__ tab,
                                              unsigned short* __restrict__ t1eH) {
    int wave = threadIdx.x >> 6, lane = threadIdx.x & 63;
    int row = blockIdx.x * 4 + wave;                     // grid = 37500 exact
    int slot = lane >> 3;                                // 0..7 : edge slot
    int sl   = lane & 7;                                 // dims 8*sl .. 8*sl+7
    int s = row_ptr[row], e = row_ptr[row + 1];
    float acc[8] = {};
    for (int p = s + slot; p < e; p += 8) {
        int2  ed = edges[p];
        int   c  = ed.x;
        float v  = __int_as_float(ed.y);
        uint4 w  = *(const uint4*)&tab[c * EMBED + 8 * sl];
        union { unsigned int i; float f; } cv;
        cv.i = w.x << 16;          acc[0] += v * cv.f;
        cv.i = w.x & 0xffff0000u;  acc[1] += v * cv.f;
        cv.i = w.y << 16;          acc[2] += v * cv.f;
        cv.i = w.y & 0xffff0000u;  acc[3] += v * cv.f;
        cv.i = w.z << 16;          acc[4] += v * cv.f;
        cv.i = w.z & 0xffff0000u;  acc[5] += v * cv.f;
        cv.i = w.w << 16;          acc[6] += v * cv.f;
        cv.i = w.w & 0xffff0000u;  acc[7] += v * cv.f;
    }
#pragma unroll
    for (int k = 0; k < 8; k++) {
        acc[k] += __shfl_xor(acc[k], 8);
        acc[k] += __shfl_xor(acc[k], 16);
        acc[k] += __shfl_xor(acc[k], 32);
    }
    if (slot == 0) {
        uint4 o;
        o.x = (unsigned)f2bf(acc[0]) | ((unsigned)f2bf(acc[1]) << 16);
        o.y = (unsigned)f2bf(acc[2]) | ((unsigned)f2bf(acc[3]) << 16);
        o.z = (unsigned)f2bf(acc[4]) | ((unsigned)f2bf(acc[5]) << 16);
        o.w = (unsigned)f2bf(acc[6]) | ((unsigned)f2bf(acc[7]) << 16);
        *(uint4*)&t1eH[row * EMBED + 8 * sl] = o;
    }
}

// ---------------- dense via MFMA:
//   OUT = leakyrelu( [t1e | emb.*t1e] (Mx128) @ Wb^T (128x64) + bsum )
// Block = 256 threads (4 waves), 16 rows per wave, no LDS.
// Fragment layout (gfx950 16x16x32 bf16): A row = lane&15, k = (lane>>4)*8 + j;
//   B col = lane&15, k likewise; D row = (lane>>4)*4 + r, col = lane&15.
__global__ __launch_bounds__(256) void k_dense(const unsigned short* __restrict__ t1eH,
                                               const unsigned short* __restrict__ embH_in,
                                               unsigned short* __restrict__ embH_out,
                                               const unsigned short* __restrict__ Wb,
                                               const float* __restrict__ bsum) {
    int tid  = threadIdx.x;
    int wave = tid >> 6, lane = tid & 63;
    int r16  = lane & 15, hi = lane >> 4;
    int rowt0 = blockIdx.x * 64 + wave * 16;             // wave's row-tile base
    int row   = rowt0 + r16;
    bool ok   = row < N_NODES;

    uint4 z4 = make_uint4(0u, 0u, 0u, 0u);
    const unsigned short* trow = t1eH    + (size_t)row * EMBED;
    const unsigned short* erow = embH_in + (size_t)row * EMBED;
    uint4 t_lo = ok ? *(const uint4*)(trow + hi * 8)      : z4;   // k = hi*8..+7
    uint4 t_hi = ok ? *(const uint4*)(trow + 32 + hi * 8) : z4;   // k = 32+hi*8..
    uint4 e_lo = ok ? *(const uint4*)(erow + hi * 8)      : z4;
    uint4 e_hi = ok ? *(const uint4*)(erow + 32 + hi * 8) : z4;

    bf16x8 A0 = as_bf8(t_lo);
    bf16x8 A1 = as_bf8(t_hi);
    float ta[8], ea[8], pa[8];
    unpack8(t_lo, ta); unpack8(e_lo, ea);
#pragma unroll
    for (int j = 0; j < 8; j++) pa[j] = ta[j] * ea[j];
    bf16x8 A2 = pack8(pa);
    unpack8(t_hi, ta); unpack8(e_hi, ea);
#pragma unroll
    for (int j = 0; j < 8; j++) pa[j] = ta[j] * ea[j];
    bf16x8 A3 = pack8(pa);

#pragma unroll
    for (int nt = 0; nt < 4; nt++) {
        int wrow = nt * 16 + r16;                         // output col within Wb
        const unsigned short* wp = Wb + wrow * 128 + hi * 8;
        bf16x8 B0 = as_bf8(*(const uint4*)(wp));          // k 0..31   (W1 lo)
        bf16x8 B1 = as_bf8(*(const uint4*)(wp + 32));     // k 32..63  (W1 hi)
        bf16x8 B2 = as_bf8(*(const uint4*)(wp + 64));     // k 64..95  (W2 lo)
        bf16x8 B3 = as_bf8(*(const uint4*)(wp + 96));     // k 96..127 (W2 hi)
        f32x4 c = {0.f, 0.f, 0.f, 0.f};
        c = __builtin_amdgcn_mfma_f32_16x16x32_bf16(A0, B0, c, 0, 0, 0);
        c = __builtin_amdgcn_mfma_f32_16x16x32_bf16(A1, B1, c, 0, 0, 0);
        c = __builtin_amdgcn_mfma_f32_16x16x32_bf16(A2, B2, c, 0, 0, 0);
        c = __builtin_amdgcn_mfma_f32_16x16x32_bf16(A3, B3, c, 0, 0, 0);

        int col = nt * 16 + r16;
        float bias = bsum[col];
#pragma unroll
        for (int r = 0; r < 4; r++) {
            int orow = rowt0 + hi * 4 + r;
            if (orow < N_NODES) {
                float v = c[r] + bias;
                v = (v > 0.f) ? v : 0.01f * v;
                embH_out[(size_t)orow * EMBED + col] = f2bf(v);
            }
        }
    }
}

// ---------------- scoring ----------------
__global__ __launch_bounds__(256) void k_score0(const float* __restrict__ ue,
                                                const float* __restrict__ ie,
                                                const int* __restrict__ u,
                                                const int* __restrict__ ii,
                                                const int* __restrict__ jj,
                                                float* __restrict__ posAcc,
                                                float* __restrict__ negAcc) {
    int wave = threadIdx.x >> 6, lane = threadIdx.x & 63;
    int b = blockIdx.x * 4 + wave;                       // grid = 2048 exact
    float eu = ue[u[b]  * EMBED + lane];
    float ep = ie[ii[b] * EMBED + lane];
    float en = ie[jj[b] * EMBED + lane];
    float p = eu * ep, n = eu * en;
    for (int o = 1; o < 64; o <<= 1) {
        p += __shfl_xor(p, o);
        n += __shfl_xor(n, o);
    }
    if (lane == 0) {
        posAcc[b] += p;
        negAcc[b] += n;
    }
}

__global__ __launch_bounds__(256) void k_score1(const unsigned short* __restrict__ tab,
                                                const int* __restrict__ u,
                                                const int* __restrict__ ii,
                                                const int* __restrict__ jj,
                                                float* __restrict__ posAcc,
                                                float* __restrict__ negAcc) {
    int wave = threadIdx.x >> 6, lane = threadIdx.x & 63;
    int b = blockIdx.x * 4 + wave;                       // grid = 2048 exact
    int ru = u[b];
    int ri = N_USERS + ii[b];
    int rj = N_USERS + jj[b];
    float eu = bf2f(tab[ru * EMBED + lane]);
    float ep = bf2f(tab[ri * EMBED + lane]);
    float en = bf2f(tab[rj * EMBED + lane]);
    float su = eu * eu, sp = ep * ep, sn = en * en;
    for (int o = 1; o < 64; o <<= 1) {
        su += __shfl_xor(su, o);
        sp += __shfl_xor(sp, o);
        sn += __shfl_xor(sn, o);
    }
    eu /= fmaxf(sqrtf(su), 1e-12f);
    ep /= fmaxf(sqrtf(sp), 1e-12f);
    en /= fmaxf(sqrtf(sn), 1e-12f);
    float p = eu * ep, n = eu * en;
    for (int o = 1; o < 64; o <<= 1) {
        p += __shfl_xor(p, o);
        n += __shfl_xor(n, o);
    }
    if (lane == 0) {
        posAcc[b] += p;
        negAcc[b] += n;
    }
}

// ---------------- final loss ----------------
__global__ __launch_bounds__(256) void k_loss(const float* __restrict__ pa,
                                              const float* __restrict__ na,
                                              float* __restrict__ out) {
    int b = blockIdx.x * 256 + threadIdx.x;              // grid = 32 exact
    float z = pa[b] - na[b];
    float x = -z;
    float sp = fmaxf(x, 0.f) + log1pf(expf(-fabsf(x)));  // softplus(-z)
    for (int o = 1; o < 64; o <<= 1) sp += __shfl_xor(sp, o);
    __shared__ float s[4];
    int wave = threadIdx.x >> 6, lane = threadIdx.x & 63;
    if (lane == 0) s[wave] = sp;
    __syncthreads();
    if (threadIdx.x == 0) {
        float t = s[0] + s[1] + s[2] + s[3];
        atomicAdd(out, t * (1.f / (float)BATCH));
    }
}

extern "C" void kernel_launch(void* const* d_in, const int* in_sizes, int n_in,
                              void* d_out, int out_size, void* d_ws, size_t ws_size,
                              hipStream_t stream) {
    const float* user_emb = (const float*)d_in[0];
    const float* W1       = (const float*)d_in[2];
    const float* b1       = (const float*)d_in[3];
    const float* W2       = (const float*)d_in[4];
    const float* b2       = (const float*)d_in[5];
    const float* item_emb = (const float*)d_in[1];
    const float* adj_vals = (const float*)d_in[6];
    const int*   adj_rows = (const int*)d_in[7];
    const int*   adj_cols = (const int*)d_in[8];
    const int*   u_idx    = (const int*)d_in[9];
    const int*   i_idx    = (const int*)d_in[10];
    const int*   j_idx    = (const int*)d_in[11];
    float* out = (float*)d_out;

    // workspace layout (bytes) — 94,065,664 total (validated footprint)
    // region [0, 38,400,000): time-shared:
    //   CSR:   bucketed int4[2M] @ +0 (32,000,000), bkt_* @ +32,000,000..
    //   layers: t1eH bf16 @ +0 (19,200,000); Wb/bsum @ +20,000,000 (written post-bucketC)
    char* ws = (char*)d_ws;
    unsigned short* t1eH       = (unsigned short*)(ws);
    int4*           bucketed   = (int4*)(ws);
    unsigned short* Wb         = (unsigned short*)(ws + 20000000);    // 49,152 B
    float*          bsum       = (float*)(ws + 20100000);             // 768 B
    int*            bkt_count  = (int*)(ws + 32000000);               // 293 ints
    int*            bkt_base   = (int*)(ws + 32004096);               // 294 ints
    int*            bkt_cursor = (int*)(ws + 32008192);               // 293 ints
    unsigned short* HA         = (unsigned short*)(ws + 38400000);    // 19,200,000
    unsigned short* HB         = (unsigned short*)(ws + 57600000);    // 19,200,000
    int*            row_ptr    = (int*)(ws + 76800000);               // 600,004
    int2*           edges      = (int2*)(ws + 78000128);              // 16,000,000
    float*          posAcc     = (float*)(ws + 94000128);             // 32,768
    float*          negAcc     = (float*)(ws + 94032896);             // 32,768

    hipMemsetAsync(bkt_count, 0, 4096, stream);
    hipMemsetAsync(posAcc, 0, 2 * BATCH * sizeof(float), stream);
    hipMemsetAsync(d_out, 0, sizeof(float), stream);

    // bf16 gather table from split inputs (also serves as the concat)
    k_tobf16<<<(N_NODES * EMBED / 4 + 255) / 256, 256, 0, stream>>>(
        (const float4*)user_emb, (const float4*)item_emb, (ushort4*)HA);

    // CSR build: bucket count -> bucket scan -> chunked bucket scatter -> per-bucket sort
    k_bkt_count<<<(N_EDGES / 4 + 255) / 256, 256, 0, stream>>>(adj_rows, bkt_count);
    k_bkt_scan<<<1, 512, 0, stream>>>(bkt_count, bkt_base, bkt_cursor, row_ptr);
    k_bucketA<<<(N_EDGES + EPB - 1) / EPB, 256, 0, stream>>>(adj_rows, adj_cols, adj_vals,
                                                             bkt_cursor, bucketed);
    k_bucketC<<<NBKT, 1024, 0, stream>>>(bkt_base, bucketed, row_ptr, edges);

    // pack bf16 weights + bias (after bucketC: shares the bucketed region)
    k_wprep<<<97, 256, 0, stream>>>(W1, b1, W2, b2, Wb, bsum);

    // layer-0 scoring on raw f32 inputs (exact)
    k_score0<<<BATCH / 4, 256, 0, stream>>>(user_emb, item_emb, u_idx, i_idx, j_idx,
                                            posAcc, negAcc);

    const int SGRID = N_NODES / 4;        // 37500 (wave per row)
    const int DGRID = (N_NODES + 63) / 64;

    // layer 0: HA -> t1eH -> HB
    k_spmm<<<SGRID, 256, 0, stream>>>(row_ptr, edges, HA, t1eH);
    k_dense<<<DGRID, 256, 0, stream>>>(t1eH, HA, HB, Wb, bsum);
    k_score1<<<BATCH / 4, 256, 0, stream>>>(HB, u_idx, i_idx, j_idx, posAcc, negAcc);

    // layer 1: HB -> t1eH -> HA
    k_spmm<<<SGRID, 256, 0, stream>>>(row_ptr, edges, HB, t1eH);
    k_dense<<<DGRID, 256, 0, stream>>>(t1eH, HB, HA, Wb + 8192, bsum + 64);
    k_score1<<<BATCH / 4, 256, 0, stream>>>(HA, u_idx, i_idx, j_idx, posAcc, negAcc);

    // layer 2: HA -> t1eH -> HB
    k_spmm<<<SGRID, 256, 0, stream>>>(row_ptr, edges, HA, t1eH);
    k_dense<<<DGRID, 256, 0, stream>>>(t1eH, HA, HB, Wb + 16384, bsum + 128);
    k_score1<<<BATCH / 4, 256, 0, stream>>>(HB, u_idx, i_idx, j_idx, posAcc, negAcc);

    k_loss<<<BATCH / 256, 256, 0, stream>>>(posAcc, negAcc, out);
}

// Round 9
// 342.799 us; speedup vs baseline: 3.4620x; 1.2406x over previous
//
#include <hip/hip_runtime.h>
#include <hip/hip_bf16.h>
#include <math.h>

#define N_USERS 50000
#define N_ITEMS 100000
#define N_NODES 150000
#define N_EDGES 2000000
#define EMBED 64
#define N_LAYERS 3
#define BATCH 8192
#define BATCH3 (3 * BATCH)                                // 24576 truncated rows

#define BSHIFT 9
#define BROWS 512                                         // rows per bucket
#define NBKT ((N_NODES + BROWS - 1) / BROWS)              // 293
#define EPB 4096                                          // edges per phase-A block

typedef __bf16 bf16x8 __attribute__((ext_vector_type(8)));
typedef float  f32x4  __attribute__((ext_vector_type(4)));

__device__ __forceinline__ float bf2f(unsigned short u) {
    union { unsigned int i; float f; } c; c.i = ((unsigned int)u) << 16; return c.f;
}
__device__ __forceinline__ unsigned short f2bf(float f) {
    __hip_bfloat16 h = __float2bfloat16(f);               // RNE
    union { __hip_bfloat16 h; unsigned short u; } c; c.h = h; return c.u;
}
__device__ __forceinline__ bf16x8 as_bf8(uint4 u) {
    union { uint4 u; bf16x8 v; } c; c.u = u; return c.v;
}
__device__ __forceinline__ void unpack8(uint4 u, float* f) {
    union { unsigned int i; float x; } c;
    c.i = u.x << 16; f[0] = c.x; c.i = u.x & 0xffff0000u; f[1] = c.x;
    c.i = u.y << 16; f[2] = c.x; c.i = u.y & 0xffff0000u; f[3] = c.x;
    c.i = u.z << 16; f[4] = c.x; c.i = u.z & 0xffff0000u; f[5] = c.x;
    c.i = u.w << 16; f[6] = c.x; c.i = u.w & 0xffff0000u; f[7] = c.x;
}
__device__ __forceinline__ bf16x8 pack8(const float* f) {
    union { unsigned short s[8]; bf16x8 v; } u;
#pragma unroll
    for (int j = 0; j < 8; j++) u.s[j] = f2bf(f[j]);
    return u.v;
}
__device__ __forceinline__ void gacc(uint4 w, float v, float* acc) {
    union { unsigned int i; float f; } cv;
    cv.i = w.x << 16;          acc[0] += v * cv.f;
    cv.i = w.x & 0xffff0000u;  acc[1] += v * cv.f;
    cv.i = w.y << 16;          acc[2] += v * cv.f;
    cv.i = w.y & 0xffff0000u;  acc[3] += v * cv.f;
    cv.i = w.z << 16;          acc[4] += v * cv.f;
    cv.i = w.z & 0xffff0000u;  acc[5] += v * cv.f;
    cv.i = w.w << 16;          acc[6] += v * cv.f;
    cv.i = w.w & 0xffff0000u;  acc[7] += v * cv.f;
}

// ---------------- build unified bf16 table from split f32 inputs ----------------
__global__ __launch_bounds__(256) void k_tobf16(const float4* __restrict__ ue,
                                                const float4* __restrict__ ie,
                                                ushort4* __restrict__ tab) {
    int idx = blockIdx.x * 256 + threadIdx.x;             // float4 index
    const int TOT = N_NODES * EMBED / 4;                  // 2,400,000
    const int UPART = N_USERS * EMBED / 4;                // 800,000
    if (idx < TOT) {
        float4 v = (idx < UPART) ? ue[idx] : ie[idx - UPART];
        ushort4 o;
        o.x = f2bf(v.x); o.y = f2bf(v.y); o.z = f2bf(v.z); o.w = f2bf(v.w);
        tab[idx] = o;
    }
}

// ---------------- pack [W1;W2] into bf16 Wb[l][n][k0..127] + bias sums ----------------
__global__ __launch_bounds__(256) void k_wprep(const float* __restrict__ W1,
                                               const float* __restrict__ b1,
                                               const float* __restrict__ W2,
                                               const float* __restrict__ b2,
                                               unsigned short* __restrict__ Wb,
                                               float* __restrict__ bsum) {
    int idx = blockIdx.x * 256 + threadIdx.x;
    if (idx < 3 * 64 * 128) {
        int l = idx >> 13, rem = idx & 8191;
        int n = rem >> 7, k = rem & 127;
        float w = (k < 64) ? W1[l * 4096 + n * 64 + k] : W2[l * 4096 + n * 64 + (k - 64)];
        Wb[idx] = f2bf(w);
    } else if (idx < 3 * 64 * 128 + 192) {
        int t = idx - 3 * 64 * 128;
        bsum[t] = b1[t] + b2[t];
    }
}

// ---------------- bucket-level histogram (LDS-aggregated; 293 counters) ----------------
__global__ __launch_bounds__(256) void k_bkt_count(const int* __restrict__ rows,
                                                   int* __restrict__ bkt_count) {
    __shared__ int hist[NBKT];
    int tid = threadIdx.x;
    for (int t = tid; t < NBKT; t += 256) hist[t] = 0;
    __syncthreads();
    int e = (blockIdx.x * 256 + tid) * 4;
    if (e + 3 < N_EDGES) {
        int4 r = *(const int4*)&rows[e];
        atomicAdd(&hist[r.x >> BSHIFT], 1);
        atomicAdd(&hist[r.y >> BSHIFT], 1);
        atomicAdd(&hist[r.z >> BSHIFT], 1);
        atomicAdd(&hist[r.w >> BSHIFT], 1);
    } else {
        for (int k = 0; k < 4; k++)
            if (e + k < N_EDGES) atomicAdd(&hist[rows[e + k] >> BSHIFT], 1);
    }
    __syncthreads();
    for (int t = tid; t < NBKT; t += 256)
        if (hist[t] > 0) atomicAdd(&bkt_count[t], hist[t]);
}

// ---------------- scan of 293 bucket counts (1 block, 512 threads) ----------------
__global__ __launch_bounds__(512) void k_bkt_scan(const int* __restrict__ bkt_count,
                                                  int* __restrict__ bkt_base,
                                                  int* __restrict__ bkt_cursor,
                                                  int* __restrict__ row_ptr) {
    int tid = threadIdx.x;
    int x = (tid < NBKT) ? bkt_count[tid] : 0;
    int lane = tid & 63, wid = tid >> 6;
    int v = x;
    for (int o = 1; o < 64; o <<= 1) {
        int t = __shfl_up(v, o);
        if (lane >= o) v += t;
    }
    __shared__ int wsum[8];
    if (lane == 63) wsum[wid] = v;
    __syncthreads();
    int add = 0;
    for (int w = 0; w < wid; w++) add += wsum[w];
    int incl = add + v;
    int excl = incl - x;
    if (tid < NBKT) {
        bkt_base[tid]   = excl;
        bkt_cursor[tid] = excl;
    }
    if (tid == NBKT - 1) {
        bkt_base[NBKT]    = incl;          // == N_EDGES
        row_ptr[N_NODES]  = incl;
    }
}

// ---------------- Phase A: bucket edges into bucket-contiguous scratch ----------------
__global__ __launch_bounds__(256) void k_bucketA(const int* __restrict__ rows,
                                                 const int* __restrict__ cols,
                                                 const float* __restrict__ vals,
                                                 int* __restrict__ bkt_cursor,
                                                 int4* __restrict__ bucketed) {
    __shared__ int sr[EPB];
    __shared__ int sc[EPB];
    __shared__ int sv[EPB];
    __shared__ int hist[NBKT];
    __shared__ int cbase[NBKT];
    int tid = threadIdx.x;
    int e0 = blockIdx.x * EPB;
    int cnt = N_EDGES - e0; if (cnt > EPB) cnt = EPB;

    for (int i = tid; i < cnt; i += 256) {
        sr[i] = rows[e0 + i];
        sc[i] = cols[e0 + i];
        sv[i] = __float_as_int(vals[e0 + i]);
    }
    for (int t = tid; t < NBKT; t += 256) hist[t] = 0;
    __syncthreads();
    for (int i = tid; i < cnt; i += 256) atomicAdd(&hist[sr[i] >> BSHIFT], 1);
    __syncthreads();
    for (int t = tid; t < NBKT; t += 256)
        cbase[t] = (hist[t] > 0) ? atomicAdd(&bkt_cursor[t], hist[t]) : 0;
    __syncthreads();
    for (int t = tid; t < NBKT; t += 256) hist[t] = 0;
    __syncthreads();
    for (int i = tid; i < cnt; i += 256) {
        int b = sr[i] >> BSHIFT;
        int off = atomicAdd(&hist[b], 1);
        bucketed[cbase[b] + off] = make_int4(sr[i], sc[i], sv[i], 0);
    }
}

// ---------------- Phase C: per-bucket row_ptr build + scatter (LDS atomics only) -------
__global__ __launch_bounds__(1024) void k_bucketC(const int* __restrict__ bkt_base,
                                                  const int4* __restrict__ bucketed,
                                                  int* __restrict__ row_ptr,
                                                  int2* __restrict__ edges) {
    __shared__ int hist[BROWS];
    __shared__ int ssum[BROWS];
    __shared__ int cur[BROWS];
    int b = blockIdx.x, tid = threadIdx.x;
    int base = bkt_base[b];
    int cnt  = bkt_base[b + 1] - base;
    int row0 = b << BSHIFT;

    if (tid < BROWS) hist[tid] = 0;
    __syncthreads();
    for (int i = tid; i < cnt; i += 1024)
        atomicAdd(&hist[bucketed[base + i].x - row0], 1);
    __syncthreads();
    int own = 0;
    if (tid < BROWS) { own = hist[tid]; ssum[tid] = own; }
    __syncthreads();
    for (int off = 1; off < BROWS; off <<= 1) {
        int t = 0;
        if (tid < BROWS && tid >= off) t = ssum[tid - off];
        __syncthreads();
        if (tid < BROWS) ssum[tid] += t;
        __syncthreads();
    }
    if (tid < BROWS) {
        int excl = ssum[tid] - own;
        int grow = row0 + tid;
        if (grow < N_NODES) row_ptr[grow] = base + excl;
        cur[tid] = excl;
    }
    __syncthreads();
    for (int i = tid; i < cnt; i += 1024) {
        int4 ed = bucketed[base + i];
        int lr  = ed.x - row0;
        int off = atomicAdd(&cur[lr], 1);
        edges[base + off] = make_int2(ed.y, ed.z);
    }
}

// ---------------- SpMM: t1eH = A @ embH (bf16, wave/row, 8 slots, 2x unroll) ----------
__global__ __launch_bounds__(256) void k_spmm(const int*  __restrict__ row_ptr,
                                              const int2* __restrict__ edges,
                                              const unsigned short* __restrict__ tab,
                                              unsigned short* __restrict__ t1eH) {
    int wave = threadIdx.x >> 6, lane = threadIdx.x & 63;
    int row = blockIdx.x * 4 + wave;                     // grid = 37500 exact
    int slot = lane >> 3;                                // 0..7 : edge slot
    int sl   = lane & 7;                                 // dims 8*sl .. 8*sl+7
    int s = row_ptr[row], e = row_ptr[row + 1];
    float acc[8] = {};
    int p = s + slot;
    for (; p + 8 < e; p += 16) {
        int2 ed0 = edges[p];
        int2 ed1 = edges[p + 8];
        uint4 w0 = *(const uint4*)&tab[ed0.x * EMBED + 8 * sl];
        uint4 w1 = *(const uint4*)&tab[ed1.x * EMBED + 8 * sl];
        gacc(w0, __int_as_float(ed0.y), acc);
        gacc(w1, __int_as_float(ed1.y), acc);
    }
    if (p < e) {
        int2 ed = edges[p];
        uint4 w = *(const uint4*)&tab[ed.x * EMBED + 8 * sl];
        gacc(w, __int_as_float(ed.y), acc);
    }
#pragma unroll
    for (int k = 0; k < 8; k++) {
        acc[k] += __shfl_xor(acc[k], 8);
        acc[k] += __shfl_xor(acc[k], 16);
        acc[k] += __shfl_xor(acc[k], 32);
    }
    if (slot == 0) {
        uint4 o;
        o.x = (unsigned)f2bf(acc[0]) | ((unsigned)f2bf(acc[1]) << 16);
        o.y = (unsigned)f2bf(acc[2]) | ((unsigned)f2bf(acc[3]) << 16);
        o.z = (unsigned)f2bf(acc[4]) | ((unsigned)f2bf(acc[5]) << 16);
        o.w = (unsigned)f2bf(acc[6]) | ((unsigned)f2bf(acc[7]) << 16);
        *(uint4*)&t1eH[row * EMBED + 8 * sl] = o;
    }
}

__device__ __forceinline__ int map_row(int bb, const int* u, const int* ii, const int* jj) {
    if (bb < BATCH) return u[bb];
    if (bb < 2 * BATCH) return N_USERS + ii[bb - BATCH];
    return N_USERS + jj[bb - 2 * BATCH];
}

// ---------------- truncated SpMM: only the 24576 batch-needed rows --------------------
__global__ __launch_bounds__(256) void k_spmm_t(const int*  __restrict__ row_ptr,
                                                const int2* __restrict__ edges,
                                                const unsigned short* __restrict__ tab,
                                                unsigned short* __restrict__ t1eS,
                                                const int* __restrict__ u,
                                                const int* __restrict__ ii,
                                                const int* __restrict__ jj) {
    int wave = threadIdx.x >> 6, lane = threadIdx.x & 63;
    int bb = blockIdx.x * 4 + wave;                      // grid = 6144 exact
    int row = map_row(bb, u, ii, jj);
    int slot = lane >> 3, sl = lane & 7;
    int s = row_ptr[row], e = row_ptr[row + 1];
    float acc[8] = {};
    int p = s + slot;
    for (; p + 8 < e; p += 16) {
        int2 ed0 = edges[p];
        int2 ed1 = edges[p + 8];
        uint4 w0 = *(const uint4*)&tab[ed0.x * EMBED + 8 * sl];
        uint4 w1 = *(const uint4*)&tab[ed1.x * EMBED + 8 * sl];
        gacc(w0, __int_as_float(ed0.y), acc);
        gacc(w1, __int_as_float(ed1.y), acc);
    }
    if (p < e) {
        int2 ed = edges[p];
        uint4 w = *(const uint4*)&tab[ed.x * EMBED + 8 * sl];
        gacc(w, __int_as_float(ed.y), acc);
    }
#pragma unroll
    for (int k = 0; k < 8; k++) {
        acc[k] += __shfl_xor(acc[k], 8);
        acc[k] += __shfl_xor(acc[k], 16);
        acc[k] += __shfl_xor(acc[k], 32);
    }
    if (slot == 0) {
        uint4 o;
        o.x = (unsigned)f2bf(acc[0]) | ((unsigned)f2bf(acc[1]) << 16);
        o.y = (unsigned)f2bf(acc[2]) | ((unsigned)f2bf(acc[3]) << 16);
        o.z = (unsigned)f2bf(acc[4]) | ((unsigned)f2bf(acc[5]) << 16);
        o.w = (unsigned)f2bf(acc[6]) | ((unsigned)f2bf(acc[7]) << 16);
        *(uint4*)&t1eS[bb * EMBED + 8 * sl] = o;
    }
}

// ---------------- dense via MFMA (full table version) ----------------
__global__ __launch_bounds__(256) void k_dense(const unsigned short* __restrict__ t1eH,
                                               const unsigned short* __restrict__ embH_in,
                                               unsigned short* __restrict__ embH_out,
                                               const unsigned short* __restrict__ Wb,
                                               const float* __restrict__ bsum) {
    int tid  = threadIdx.x;
    int wave = tid >> 6, lane = tid & 63;
    int r16  = lane & 15, hi = lane >> 4;
    int rowt0 = blockIdx.x * 64 + wave * 16;
    int row   = rowt0 + r16;
    bool ok   = row < N_NODES;

    uint4 z4 = make_uint4(0u, 0u, 0u, 0u);
    const unsigned short* trow = t1eH    + (size_t)row * EMBED;
    const unsigned short* erow = embH_in + (size_t)row * EMBED;
    uint4 t_lo = ok ? *(const uint4*)(trow + hi * 8)      : z4;
    uint4 t_hi = ok ? *(const uint4*)(trow + 32 + hi * 8) : z4;
    uint4 e_lo = ok ? *(const uint4*)(erow + hi * 8)      : z4;
    uint4 e_hi = ok ? *(const uint4*)(erow + 32 + hi * 8) : z4;

    bf16x8 A0 = as_bf8(t_lo);
    bf16x8 A1 = as_bf8(t_hi);
    float ta[8], ea[8], pa[8];
    unpack8(t_lo, ta); unpack8(e_lo, ea);
#pragma unroll
    for (int j = 0; j < 8; j++) pa[j] = ta[j] * ea[j];
    bf16x8 A2 = pack8(pa);
    unpack8(t_hi, ta); unpack8(e_hi, ea);
#pragma unroll
    for (int j = 0; j < 8; j++) pa[j] = ta[j] * ea[j];
    bf16x8 A3 = pack8(pa);

#pragma unroll
    for (int nt = 0; nt < 4; nt++) {
        int wrow = nt * 16 + r16;
        const unsigned short* wp = Wb + wrow * 128 + hi * 8;
        bf16x8 B0 = as_bf8(*(const uint4*)(wp));
        bf16x8 B1 = as_bf8(*(const uint4*)(wp + 32));
        bf16x8 B2 = as_bf8(*(const uint4*)(wp + 64));
        bf16x8 B3 = as_bf8(*(const uint4*)(wp + 96));
        f32x4 c = {0.f, 0.f, 0.f, 0.f};
        c = __builtin_amdgcn_mfma_f32_16x16x32_bf16(A0, B0, c, 0, 0, 0);
        c = __builtin_amdgcn_mfma_f32_16x16x32_bf16(A1, B1, c, 0, 0, 0);
        c = __builtin_amdgcn_mfma_f32_16x16x32_bf16(A2, B2, c, 0, 0, 0);
        c = __builtin_amdgcn_mfma_f32_16x16x32_bf16(A3, B3, c, 0, 0, 0);

        int col = nt * 16 + r16;
        float bias = bsum[col];
#pragma unroll
        for (int r = 0; r < 4; r++) {
            int orow = rowt0 + hi * 4 + r;
            if (orow < N_NODES) {
                float v = c[r] + bias;
                v = (v > 0.f) ? v : 0.01f * v;
                embH_out[(size_t)orow * EMBED + col] = f2bf(v);
            }
        }
    }
}

// ---------------- truncated dense: 24576 batch rows, emb gathered via map ------------
__global__ __launch_bounds__(256) void k_dense_t(const unsigned short* __restrict__ t1eS,
                                                 const unsigned short* __restrict__ embH_in,
                                                 unsigned short* __restrict__ t2out,
                                                 const unsigned short* __restrict__ Wb,
                                                 const float* __restrict__ bsum,
                                                 const int* __restrict__ u,
                                                 const int* __restrict__ ii,
                                                 const int* __restrict__ jj) {
    int tid  = threadIdx.x;
    int wave = tid >> 6, lane = tid & 63;
    int r16  = lane & 15, hi = lane >> 4;
    int rowt0 = blockIdx.x * 64 + wave * 16;             // grid = 384 exact -> bb < 24576
    int bb   = rowt0 + r16;
    int nrow = map_row(bb, u, ii, jj);

    const unsigned short* trow = t1eS    + (size_t)bb   * EMBED;
    const unsigned short* erow = embH_in + (size_t)nrow * EMBED;
    uint4 t_lo = *(const uint4*)(trow + hi * 8);
    uint4 t_hi = *(const uint4*)(trow + 32 + hi * 8);
    uint4 e_lo = *(const uint4*)(erow + hi * 8);
    uint4 e_hi = *(const uint4*)(erow + 32 + hi * 8);

    bf16x8 A0 = as_bf8(t_lo);
    bf16x8 A1 = as_bf8(t_hi);
    float ta[8], ea[8], pa[8];
    unpack8(t_lo, ta); unpack8(e_lo, ea);
#pragma unroll
    for (int j = 0; j < 8; j++) pa[j] = ta[j] * ea[j];
    bf16x8 A2 = pack8(pa);
    unpack8(t_hi, ta); unpack8(e_hi, ea);
#pragma unroll
    for (int j = 0; j < 8; j++) pa[j] = ta[j] * ea[j];
    bf16x8 A3 = pack8(pa);

#pragma unroll
    for (int nt = 0; nt < 4; nt++) {
        int wrow = nt * 16 + r16;
        const unsigned short* wp = Wb + wrow * 128 + hi * 8;
        bf16x8 B0 = as_bf8(*(const uint4*)(wp));
        bf16x8 B1 = as_bf8(*(const uint4*)(wp + 32));
        bf16x8 B2 = as_bf8(*(const uint4*)(wp + 64));
        bf16x8 B3 = as_bf8(*(const uint4*)(wp + 96));
        f32x4 c = {0.f, 0.f, 0.f, 0.f};
        c = __builtin_amdgcn_mfma_f32_16x16x32_bf16(A0, B0, c, 0, 0, 0);
        c = __builtin_amdgcn_mfma_f32_16x16x32_bf16(A1, B1, c, 0, 0, 0);
        c = __builtin_amdgcn_mfma_f32_16x16x32_bf16(A2, B2, c, 0, 0, 0);
        c = __builtin_amdgcn_mfma_f32_16x16x32_bf16(A3, B3, c, 0, 0, 0);

        int col = nt * 16 + r16;
        float bias = bsum[col];
#pragma unroll
        for (int r = 0; r < 4; r++) {
            int obb = rowt0 + hi * 4 + r;
            float v = c[r] + bias;
            v = (v > 0.f) ? v : 0.01f * v;
            t2out[(size_t)obb * EMBED + col] = f2bf(v);
        }
    }
}

// ---------------- scoring ----------------
__global__ __launch_bounds__(256) void k_score0(const float* __restrict__ ue,
                                                const float* __restrict__ ie,
                                                const int* __restrict__ u,
                                                const int* __restrict__ ii,
                                                const int* __restrict__ jj,
                                                float* __restrict__ posAcc,
                                                float* __restrict__ negAcc) {
    int wave = threadIdx.x >> 6, lane = threadIdx.x & 63;
    int b = blockIdx.x * 4 + wave;                       // grid = 2048 exact
    float eu = ue[u[b]  * EMBED + lane];
    float ep = ie[ii[b] * EMBED + lane];
    float en = ie[jj[b] * EMBED + lane];
    float p = eu * ep, n = eu * en;
    for (int o = 1; o < 64; o <<= 1) {
        p += __shfl_xor(p, o);
        n += __shfl_xor(n, o);
    }
    if (lane == 0) {
        posAcc[b] += p;
        negAcc[b] += n;
    }
}

__global__ __launch_bounds__(256) void k_score1(const unsigned short* __restrict__ tab,
                                                const int* __restrict__ u,
                                                const int* __restrict__ ii,
                                                const int* __restrict__ jj,
                                                float* __restrict__ posAcc,
                                                float* __restrict__ negAcc) {
    int wave = threadIdx.x >> 6, lane = threadIdx.x & 63;
    int b = blockIdx.x * 4 + wave;                       // grid = 2048 exact
    int ru = u[b];
    int ri = N_USERS + ii[b];
    int rj = N_USERS + jj[b];
    float eu = bf2f(tab[ru * EMBED + lane]);
    float ep = bf2f(tab[ri * EMBED + lane]);
    float en = bf2f(tab[rj * EMBED + lane]);
    float su = eu * eu, sp = ep * ep, sn = en * en;
    for (int o = 1; o < 64; o <<= 1) {
        su += __shfl_xor(su, o);
        sp += __shfl_xor(sp, o);
        sn += __shfl_xor(sn, o);
    }
    eu /= fmaxf(sqrtf(su), 1e-12f);
    ep /= fmaxf(sqrtf(sp), 1e-12f);
    en /= fmaxf(sqrtf(sn), 1e-12f);
    float p = eu * ep, n = eu * en;
    for (int o = 1; o < 64; o <<= 1) {
        p += __shfl_xor(p, o);
        n += __shfl_xor(n, o);
    }
    if (lane == 0) {
        posAcc[b] += p;
        negAcc[b] += n;
    }
}

// truncated-layer scoring: sequential reads of t2out rows (b, B+b, 2B+b)
__global__ __launch_bounds__(256) void k_score1t(const unsigned short* __restrict__ t2out,
                                                 float* __restrict__ posAcc,
                                                 float* __restrict__ negAcc) {
    int wave = threadIdx.x >> 6, lane = threadIdx.x & 63;
    int b = blockIdx.x * 4 + wave;                       // grid = 2048 exact
    float eu = bf2f(t2out[(size_t)b * EMBED + lane]);
    float ep = bf2f(t2out[(size_t)(BATCH + b) * EMBED + lane]);
    float en = bf2f(t2out[(size_t)(2 * BATCH + b) * EMBED + lane]);
    float su = eu * eu, sp = ep * ep, sn = en * en;
    for (int o = 1; o < 64; o <<= 1) {
        su += __shfl_xor(su, o);
        sp += __shfl_xor(sp, o);
        sn += __shfl_xor(sn, o);
    }
    eu /= fmaxf(sqrtf(su), 1e-12f);
    ep /= fmaxf(sqrtf(sp), 1e-12f);
    en /= fmaxf(sqrtf(sn), 1e-12f);
    float p = eu * ep, n = eu * en;
    for (int o = 1; o < 64; o <<= 1) {
        p += __shfl_xor(p, o);
        n += __shfl_xor(n, o);
    }
    if (lane == 0) {
        posAcc[b] += p;
        negAcc[b] += n;
    }
}

// ---------------- final loss ----------------
__global__ __launch_bounds__(256) void k_loss(const float* __restrict__ pa,
                                              const float* __restrict__ na,
                                              float* __restrict__ out) {
    int b = blockIdx.x * 256 + threadIdx.x;              // grid = 32 exact
    float z = pa[b] - na[b];
    float x = -z;
    float sp = fmaxf(x, 0.f) + log1pf(expf(-fabsf(x)));  // softplus(-z)
    for (int o = 1; o < 64; o <<= 1) sp += __shfl_xor(sp, o);
    __shared__ float s[4];
    int wave = threadIdx.x >> 6, lane = threadIdx.x & 63;
    if (lane == 0) s[wave] = sp;
    __syncthreads();
    if (threadIdx.x == 0) {
        float t = s[0] + s[1] + s[2] + s[3];
        atomicAdd(out, t * (1.f / (float)BATCH));
    }
}

extern "C" void kernel_launch(void* const* d_in, const int* in_sizes, int n_in,
                              void* d_out, int out_size, void* d_ws, size_t ws_size,
                              hipStream_t stream) {
    const float* user_emb = (const float*)d_in[0];
    const float* item_emb = (const float*)d_in[1];
    const float* W1       = (const float*)d_in[2];
    const float* b1       = (const float*)d_in[3];
    const float* W2       = (const float*)d_in[4];
    const float* b2       = (const float*)d_in[5];
    const float* adj_vals = (const float*)d_in[6];
    const int*   adj_rows = (const int*)d_in[7];
    const int*   adj_cols = (const int*)d_in[8];
    const int*   u_idx    = (const int*)d_in[9];
    const int*   i_idx    = (const int*)d_in[10];
    const int*   j_idx    = (const int*)d_in[11];
    float* out = (float*)d_out;

    // workspace layout (bytes) — 94,065,664 total (validated footprint)
    // region [0, 38,400,000): time-shared:
    //   CSR:    bucketed int4[2M] @ +0 (32,000,000), bkt_* @ +32,000,000..
    //   layers: t1eH bf16 @ +0 (19,200,000); layer-2: t1eS @ +0, t2out @ +4,000,000
    //   Wb/bsum @ +20,000,000 (written post-bucketC)
    char* ws = (char*)d_ws;
    unsigned short* t1eH       = (unsigned short*)(ws);
    unsigned short* t1eS       = (unsigned short*)(ws);               // 3,145,728 B
    unsigned short* t2out      = (unsigned short*)(ws + 4000000);     // 3,145,728 B
    int4*           bucketed   = (int4*)(ws);
    unsigned short* Wb         = (unsigned short*)(ws + 20000000);    // 49,152 B
    float*          bsum       = (float*)(ws + 20100000);             // 768 B
    int*            bkt_count  = (int*)(ws + 32000000);               // 293 ints
    int*            bkt_base   = (int*)(ws + 32004096);               // 294 ints
    int*            bkt_cursor = (int*)(ws + 32008192);               // 293 ints
    unsigned short* HA         = (unsigned short*)(ws + 38400000);    // 19,200,000
    unsigned short* HB         = (unsigned short*)(ws + 57600000);    // 19,200,000
    int*            row_ptr    = (int*)(ws + 76800000);               // 600,004
    int2*           edges      = (int2*)(ws + 78000128);              // 16,000,000
    float*          posAcc     = (float*)(ws + 94000128);             // 32,768
    float*          negAcc     = (float*)(ws + 94032896);             // 32,768

    hipMemsetAsync(bkt_count, 0, 4096, stream);
    hipMemsetAsync(posAcc, 0, 2 * BATCH * sizeof(float), stream);    // covers negAcc too
    hipMemsetAsync(d_out, 0, sizeof(float), stream);

    // bf16 gather table from split inputs (also serves as the concat)
    k_tobf16<<<(N_NODES * EMBED / 4 + 255) / 256, 256, 0, stream>>>(
        (const float4*)user_emb, (const float4*)item_emb, (ushort4*)HA);

    // CSR build: bucket count -> bucket scan -> chunked bucket scatter -> per-bucket sort
    k_bkt_count<<<(N_EDGES / 4 + 255) / 256, 256, 0, stream>>>(adj_rows, bkt_count);
    k_bkt_scan<<<1, 512, 0, stream>>>(bkt_count, bkt_base, bkt_cursor, row_ptr);
    k_bucketA<<<(N_EDGES + EPB - 1) / EPB, 256, 0, stream>>>(adj_rows, adj_cols, adj_vals,
                                                             bkt_cursor, bucketed);
    k_bucketC<<<NBKT, 1024, 0, stream>>>(bkt_base, bucketed, row_ptr, edges);

    // pack bf16 weights + bias (after bucketC: shares the bucketed region)
    k_wprep<<<97, 256, 0, stream>>>(W1, b1, W2, b2, Wb, bsum);

    // layer-0 scoring on raw f32 inputs (exact)
    k_score0<<<BATCH / 4, 256, 0, stream>>>(user_emb, item_emb, u_idx, i_idx, j_idx,
                                            posAcc, negAcc);

    const int SGRID = N_NODES / 4;        // 37500 (wave per row)
    const int DGRID = (N_NODES + 63) / 64;

    // layer 0: HA -> t1eH -> HB
    k_spmm<<<SGRID, 256, 0, stream>>>(row_ptr, edges, HA, t1eH);
    k_dense<<<DGRID, 256, 0, stream>>>(t1eH, HA, HB, Wb, bsum);
    k_score1<<<BATCH / 4, 256, 0, stream>>>(HB, u_idx, i_idx, j_idx, posAcc, negAcc);

    // layer 1: HB -> t1eH -> HA
    k_spmm<<<SGRID, 256, 0, stream>>>(row_ptr, edges, HB, t1eH);
    k_dense<<<DGRID, 256, 0, stream>>>(t1eH, HB, HA, Wb + 8192, bsum + 64);
    k_score1<<<BATCH / 4, 256, 0, stream>>>(HA, u_idx, i_idx, j_idx, posAcc, negAcc);

    // layer 2 (truncated): only the 24576 batch rows
    k_spmm_t<<<BATCH3 / 4, 256, 0, stream>>>(row_ptr, edges, HA, t1eS,
                                             u_idx, i_idx, j_idx);
    k_dense_t<<<BATCH3 / 64, 256, 0, stream>>>(t1eS, HA, t2out, Wb + 16384, bsum + 128,
                                               u_idx, i_idx, j_idx);
    k_score1t<<<BATCH / 4, 256, 0, stream>>>(t2out, posAcc, negAcc);

    k_loss<<<BATCH / 256, 256, 0, stream>>>(posAcc, negAcc, out);
}

// Round 11
// 340.943 us; speedup vs baseline: 3.4809x; 1.0054x over previous
//
#include <hip/hip_runtime.h>
#include <hip/hip_bf16.h>
#include <math.h>

#define N_USERS 50000
#define N_ITEMS 100000
#define N_NODES 150000
#define N_EDGES 2000000
#define EMBED 64
#define N_LAYERS 3
#define BATCH 8192
#define BATCH3 (3 * BATCH)                                // 24576 truncated rows

#define BSHIFT 9
#define BROWS 512                                         // rows per bucket
#define NBKT ((N_NODES + BROWS - 1) / BROWS)              // 293
#define EPB 4096                                          // edges per phase-A block

typedef __bf16 bf16x8 __attribute__((ext_vector_type(8)));
typedef float  f32x4  __attribute__((ext_vector_type(4)));

__device__ __forceinline__ float bf2f(unsigned short u) {
    union { unsigned int i; float f; } c; c.i = ((unsigned int)u) << 16; return c.f;
}
__device__ __forceinline__ unsigned short f2bf(float f) {
    __hip_bfloat16 h = __float2bfloat16(f);               // RNE
    union { __hip_bfloat16 h; unsigned short u; } c; c.h = h; return c.u;
}
__device__ __forceinline__ unsigned char f2q8(float x) {  // f32 -> fp8 e4m3 (RNE)
    return (unsigned char)(__builtin_amdgcn_cvt_pk_fp8_f32(x, x, 0, false) & 0xff);
}
__device__ __forceinline__ bf16x8 as_bf8(uint4 u) {
    union { uint4 u; bf16x8 v; } c; c.u = u; return c.v;
}
__device__ __forceinline__ void unpack8(uint4 u, float* f) {
    union { unsigned int i; float x; } c;
    c.i = u.x << 16; f[0] = c.x; c.i = u.x & 0xffff0000u; f[1] = c.x;
    c.i = u.y << 16; f[2] = c.x; c.i = u.y & 0xffff0000u; f[3] = c.x;
    c.i = u.z << 16; f[4] = c.x; c.i = u.z & 0xffff0000u; f[5] = c.x;
    c.i = u.w << 16; f[6] = c.x; c.i = u.w & 0xffff0000u; f[7] = c.x;
}
__device__ __forceinline__ bf16x8 pack8(const float* f) {
    union { unsigned short s[8]; bf16x8 v; } u;
#pragma unroll
    for (int j = 0; j < 8; j++) u.s[j] = f2bf(f[j]);
    return u.v;
}
// fp8x8 (uint2) gather-accumulate: acc[0..7] += v * fp8vals
__device__ __forceinline__ void qacc(uint2 w, float v, float* acc) {
    auto f0 = __builtin_amdgcn_cvt_pk_f32_fp8(w.x, false);
    auto f1 = __builtin_amdgcn_cvt_pk_f32_fp8(w.x, true);
    auto f2 = __builtin_amdgcn_cvt_pk_f32_fp8(w.y, false);
    auto f3 = __builtin_amdgcn_cvt_pk_f32_fp8(w.y, true);
    acc[0] += v * f0[0]; acc[1] += v * f0[1];
    acc[2] += v * f1[0]; acc[3] += v * f1[1];
    acc[4] += v * f2[0]; acc[5] += v * f2[1];
    acc[6] += v * f3[0]; acc[7] += v * f3[1];
}

// ---------------- build bf16 + fp8 tables from split f32 inputs ----------------
__global__ __launch_bounds__(256) void k_tabs(const float4* __restrict__ ue,
                                              const float4* __restrict__ ie,
                                              ushort4* __restrict__ tab,
                                              unsigned int* __restrict__ q8) {
    int idx = blockIdx.x * 256 + threadIdx.x;             // float4 index
    const int TOT = N_NODES * EMBED / 4;                  // 2,400,000
    const int UPART = N_USERS * EMBED / 4;                // 800,000
    if (idx < TOT) {
        float4 v = (idx < UPART) ? ue[idx] : ie[idx - UPART];
        ushort4 o;
        o.x = f2bf(v.x); o.y = f2bf(v.y); o.z = f2bf(v.z); o.w = f2bf(v.w);
        tab[idx] = o;
        unsigned int lo = (unsigned int)__builtin_amdgcn_cvt_pk_fp8_f32(v.x, v.y, 0, false) & 0xffffu;
        unsigned int hi = (unsigned int)__builtin_amdgcn_cvt_pk_fp8_f32(v.z, v.w, 0, false) & 0xffffu;
        q8[idx] = lo | (hi << 16);
    }
}

// ---------------- pack [W1;W2] into bf16 Wb[l][n][k0..127] + bias sums ----------------
__global__ __launch_bounds__(256) void k_wprep(const float* __restrict__ W1,
                                               const float* __restrict__ b1,
                                               const float* __restrict__ W2,
                                               const float* __restrict__ b2,
                                               unsigned short* __restrict__ Wb,
                                               float* __restrict__ bsum) {
    int idx = blockIdx.x * 256 + threadIdx.x;
    if (idx < 3 * 64 * 128) {
        int l = idx >> 13, rem = idx & 8191;
        int n = rem >> 7, k = rem & 127;
        float w = (k < 64) ? W1[l * 4096 + n * 64 + k] : W2[l * 4096 + n * 64 + (k - 64)];
        Wb[idx] = f2bf(w);
    } else if (idx < 3 * 64 * 128 + 192) {
        int t = idx - 3 * 64 * 128;
        bsum[t] = b1[t] + b2[t];
    }
}

// ---------------- bucket-level histogram (LDS-aggregated; 293 counters) ----------------
__global__ __launch_bounds__(256) void k_bkt_count(const int* __restrict__ rows,
                                                   int* __restrict__ bkt_count) {
    __shared__ int hist[NBKT];
    int tid = threadIdx.x;
    for (int t = tid; t < NBKT; t += 256) hist[t] = 0;
    __syncthreads();
    int e = (blockIdx.x * 256 + tid) * 4;
    if (e + 3 < N_EDGES) {
        int4 r = *(const int4*)&rows[e];
        atomicAdd(&hist[r.x >> BSHIFT], 1);
        atomicAdd(&hist[r.y >> BSHIFT], 1);
        atomicAdd(&hist[r.z >> BSHIFT], 1);
        atomicAdd(&hist[r.w >> BSHIFT], 1);
    } else {
        for (int k = 0; k < 4; k++)
            if (e + k < N_EDGES) atomicAdd(&hist[rows[e + k] >> BSHIFT], 1);
    }
    __syncthreads();
    for (int t = tid; t < NBKT; t += 256)
        if (hist[t] > 0) atomicAdd(&bkt_count[t], hist[t]);
}

// ---------------- scan of 293 bucket counts (1 block, 512 threads) ----------------
__global__ __launch_bounds__(512) void k_bkt_scan(const int* __restrict__ bkt_count,
                                                  int* __restrict__ bkt_base,
                                                  int* __restrict__ bkt_cursor,
                                                  int* __restrict__ row_ptr) {
    int tid = threadIdx.x;
    int x = (tid < NBKT) ? bkt_count[tid] : 0;
    int lane = tid & 63, wid = tid >> 6;
    int v = x;
    for (int o = 1; o < 64; o <<= 1) {
        int t = __shfl_up(v, o);
        if (lane >= o) v += t;
    }
    __shared__ int wsum[8];
    if (lane == 63) wsum[wid] = v;
    __syncthreads();
    int add = 0;
    for (int w = 0; w < wid; w++) add += wsum[w];
    int incl = add + v;
    int excl = incl - x;
    if (tid < NBKT) {
        bkt_base[tid]   = excl;
        bkt_cursor[tid] = excl;
    }
    if (tid == NBKT - 1) {
        bkt_base[NBKT]    = incl;          // == N_EDGES
        row_ptr[N_NODES]  = incl;
    }
}

// ---------------- Phase A: bucket edges (packed lr|col,val int2) ----------------
__global__ __launch_bounds__(256) void k_bucketA(const int* __restrict__ rows,
                                                 const int* __restrict__ cols,
                                                 const float* __restrict__ vals,
                                                 int* __restrict__ bkt_cursor,
                                                 int2* __restrict__ bucketed) {
    __shared__ int sr[EPB];
    __shared__ int sc[EPB];
    __shared__ int sv[EPB];
    __shared__ int hist[NBKT];
    __shared__ int cbase[NBKT];
    int tid = threadIdx.x;
    int e0 = blockIdx.x * EPB;
    int cnt = N_EDGES - e0; if (cnt > EPB) cnt = EPB;

    for (int i = tid; i < cnt; i += 256) {
        sr[i] = rows[e0 + i];
        sc[i] = cols[e0 + i];
        sv[i] = __float_as_int(vals[e0 + i]);
    }
    for (int t = tid; t < NBKT; t += 256) hist[t] = 0;
    __syncthreads();
    for (int i = tid; i < cnt; i += 256) atomicAdd(&hist[sr[i] >> BSHIFT], 1);
    __syncthreads();
    for (int t = tid; t < NBKT; t += 256)
        cbase[t] = (hist[t] > 0) ? atomicAdd(&bkt_cursor[t], hist[t]) : 0;
    __syncthreads();
    for (int t = tid; t < NBKT; t += 256) hist[t] = 0;
    __syncthreads();
    for (int i = tid; i < cnt; i += 256) {
        int r = sr[i];
        int b = r >> BSHIFT;
        int lr = r & (BROWS - 1);
        int off = atomicAdd(&hist[b], 1);
        bucketed[cbase[b] + off] = make_int2((lr << 18) | sc[i], sv[i]);
    }
}

// ---------------- Phase C: per-bucket row_ptr build + scatter (LDS atomics only) -------
__global__ __launch_bounds__(1024) void k_bucketC(const int* __restrict__ bkt_base,
                                                  const int2* __restrict__ bucketed,
                                                  int* __restrict__ row_ptr,
                                                  int2* __restrict__ edges) {
    __shared__ int hist[BROWS];
    __shared__ int ssum[BROWS];
    __shared__ int cur[BROWS];
    int b = blockIdx.x, tid = threadIdx.x;
    int base = bkt_base[b];
    int cnt  = bkt_base[b + 1] - base;
    int row0 = b << BSHIFT;

    if (tid < BROWS) hist[tid] = 0;
    __syncthreads();
    for (int i = tid; i < cnt; i += 1024)
        atomicAdd(&hist[bucketed[base + i].x >> 18], 1);
    __syncthreads();
    int own = 0;
    if (tid < BROWS) { own = hist[tid]; ssum[tid] = own; }
    __syncthreads();
    for (int off = 1; off < BROWS; off <<= 1) {
        int t = 0;
        if (tid < BROWS && tid >= off) t = ssum[tid - off];
        __syncthreads();
        if (tid < BROWS) ssum[tid] += t;
        __syncthreads();
    }
    if (tid < BROWS) {
        int excl = ssum[tid] - own;
        int grow = row0 + tid;
        if (grow < N_NODES) row_ptr[grow] = base + excl;
        cur[tid] = excl;
    }
    __syncthreads();
    for (int i = tid; i < cnt; i += 1024) {
        int2 ed = bucketed[base + i];
        int lr  = ed.x >> 18;
        int off = atomicAdd(&cur[lr], 1);
        edges[base + off] = make_int2(ed.x & 0x3ffff, ed.y);
    }
}

// ---------------- SpMM: t1eH = A @ emb (fp8 gather, wave/row, 8 slots, 2x unroll) -----
__global__ __launch_bounds__(256) void k_spmm(const int*  __restrict__ row_ptr,
                                              const int2* __restrict__ edges,
                                              const unsigned char* __restrict__ q8,
                                              unsigned short* __restrict__ t1eH) {
    int wave = threadIdx.x >> 6, lane = threadIdx.x & 63;
    int row = blockIdx.x * 4 + wave;                     // grid = 37500 exact
    int slot = lane >> 3;                                // 0..7 : edge slot
    int sl   = lane & 7;                                 // dims 8*sl .. 8*sl+7
    int s = row_ptr[row], e = row_ptr[row + 1];
    float acc[8] = {};
    int p = s + slot;
    for (; p + 8 < e; p += 16) {
        int2 ed0 = edges[p];
        int2 ed1 = edges[p + 8];
        uint2 w0 = *(const uint2*)&q8[ed0.x * EMBED + 8 * sl];
        uint2 w1 = *(const uint2*)&q8[ed1.x * EMBED + 8 * sl];
        qacc(w0, __int_as_float(ed0.y), acc);
        qacc(w1, __int_as_float(ed1.y), acc);
    }
    if (p < e) {
        int2 ed = edges[p];
        uint2 w = *(const uint2*)&q8[ed.x * EMBED + 8 * sl];
        qacc(w, __int_as_float(ed.y), acc);
    }
#pragma unroll
    for (int k = 0; k < 8; k++) {
        acc[k] += __shfl_xor(acc[k], 8);
        acc[k] += __shfl_xor(acc[k], 16);
        acc[k] += __shfl_xor(acc[k], 32);
    }
    if (slot == 0) {
        uint4 o;
        o.x = (unsigned)f2bf(acc[0]) | ((unsigned)f2bf(acc[1]) << 16);
        o.y = (unsigned)f2bf(acc[2]) | ((unsigned)f2bf(acc[3]) << 16);
        o.z = (unsigned)f2bf(acc[4]) | ((unsigned)f2bf(acc[5]) << 16);
        o.w = (unsigned)f2bf(acc[6]) | ((unsigned)f2bf(acc[7]) << 16);
        *(uint4*)&t1eH[row * EMBED + 8 * sl] = o;
    }
}

__device__ __forceinline__ int map_row(int bb, const int* u, const int* ii, const int* jj) {
    if (bb < BATCH) return u[bb];
    if (bb < 2 * BATCH) return N_USERS + ii[bb - BATCH];
    return N_USERS + jj[bb - 2 * BATCH];
}

// ---------------- truncated SpMM: only the 24576 batch-needed rows --------------------
__global__ __launch_bounds__(256) void k_spmm_t(const int*  __restrict__ row_ptr,
                                                const int2* __restrict__ edges,
                                                const unsigned char* __restrict__ q8,
                                                unsigned short* __restrict__ t1eS,
                                                const int* __restrict__ u,
                                                const int* __restrict__ ii,
                                                const int* __restrict__ jj) {
    int wave = threadIdx.x >> 6, lane = threadIdx.x & 63;
    int bb = blockIdx.x * 4 + wave;                      // grid = 6144 exact
    int row = map_row(bb, u, ii, jj);
    int slot = lane >> 3, sl = lane & 7;
    int s = row_ptr[row], e = row_ptr[row + 1];
    float acc[8] = {};
    int p = s + slot;
    for (; p + 8 < e; p += 16) {
        int2 ed0 = edges[p];
        int2 ed1 = edges[p + 8];
        uint2 w0 = *(const uint2*)&q8[ed0.x * EMBED + 8 * sl];
        uint2 w1 = *(const uint2*)&q8[ed1.x * EMBED + 8 * sl];
        qacc(w0, __int_as_float(ed0.y), acc);
        qacc(w1, __int_as_float(ed1.y), acc);
    }
    if (p < e) {
        int2 ed = edges[p];
        uint2 w = *(const uint2*)&q8[ed.x * EMBED + 8 * sl];
        qacc(w, __int_as_float(ed.y), acc);
    }
#pragma unroll
    for (int k = 0; k < 8; k++) {
        acc[k] += __shfl_xor(acc[k], 8);
        acc[k] += __shfl_xor(acc[k], 16);
        acc[k] += __shfl_xor(acc[k], 32);
    }
    if (slot == 0) {
        uint4 o;
        o.x = (unsigned)f2bf(acc[0]) | ((unsigned)f2bf(acc[1]) << 16);
        o.y = (unsigned)f2bf(acc[2]) | ((unsigned)f2bf(acc[3]) << 16);
        o.z = (unsigned)f2bf(acc[4]) | ((unsigned)f2bf(acc[5]) << 16);
        o.w = (unsigned)f2bf(acc[6]) | ((unsigned)f2bf(acc[7]) << 16);
        *(uint4*)&t1eS[bb * EMBED + 8 * sl] = o;
    }
}

// ---------------- dense via MFMA; writes bf16 out + fp8 shadow ----------------
__global__ __launch_bounds__(256) void k_dense(const unsigned short* __restrict__ t1eH,
                                               const unsigned short* __restrict__ embH_in,
                                               unsigned short* __restrict__ embH_out,
                                               unsigned char* __restrict__ q8out,
                                               const unsigned short* __restrict__ Wb,
                                               const float* __restrict__ bsum) {
    int tid  = threadIdx.x;
    int wave = tid >> 6, lane = tid & 63;
    int r16  = lane & 15, hi = lane >> 4;
    int rowt0 = blockIdx.x * 64 + wave * 16;
    int row   = rowt0 + r16;
    bool ok   = row < N_NODES;

    uint4 z4 = make_uint4(0u, 0u, 0u, 0u);
    const unsigned short* trow = t1eH    + (size_t)row * EMBED;
    const unsigned short* erow = embH_in + (size_t)row * EMBED;
    uint4 t_lo = ok ? *(const uint4*)(trow + hi * 8)      : z4;
    uint4 t_hi = ok ? *(const uint4*)(trow + 32 + hi * 8) : z4;
    uint4 e_lo = ok ? *(const uint4*)(erow + hi * 8)      : z4;
    uint4 e_hi = ok ? *(const uint4*)(erow + 32 + hi * 8) : z4;

    bf16x8 A0 = as_bf8(t_lo);
    bf16x8 A1 = as_bf8(t_hi);
    float ta[8], ea[8], pa[8];
    unpack8(t_lo, ta); unpack8(e_lo, ea);
#pragma unroll
    for (int j = 0; j < 8; j++) pa[j] = ta[j] * ea[j];
    bf16x8 A2 = pack8(pa);
    unpack8(t_hi, ta); unpack8(e_hi, ea);
#pragma unroll
    for (int j = 0; j < 8; j++) pa[j] = ta[j] * ea[j];
    bf16x8 A3 = pack8(pa);

#pragma unroll
    for (int nt = 0; nt < 4; nt++) {
        int wrow = nt * 16 + r16;
        const unsigned short* wp = Wb + wrow * 128 + hi * 8;
        bf16x8 B0 = as_bf8(*(const uint4*)(wp));
        bf16x8 B1 = as_bf8(*(const uint4*)(wp + 32));
        bf16x8 B2 = as_bf8(*(const uint4*)(wp + 64));
        bf16x8 B3 = as_bf8(*(const uint4*)(wp + 96));
        f32x4 c = {0.f, 0.f, 0.f, 0.f};
        c = __builtin_amdgcn_mfma_f32_16x16x32_bf16(A0, B0, c, 0, 0, 0);
        c = __builtin_amdgcn_mfma_f32_16x16x32_bf16(A1, B1, c, 0, 0, 0);
        c = __builtin_amdgcn_mfma_f32_16x16x32_bf16(A2, B2, c, 0, 0, 0);
        c = __builtin_amdgcn_mfma_f32_16x16x32_bf16(A3, B3, c, 0, 0, 0);

        int col = nt * 16 + r16;
        float bias = bsum[col];
#pragma unroll
        for (int r = 0; r < 4; r++) {
            int orow = rowt0 + hi * 4 + r;
            if (orow < N_NODES) {
                float v = c[r] + bias;
                v = (v > 0.f) ? v : 0.01f * v;
                embH_out[(size_t)orow * EMBED + col] = f2bf(v);
                q8out[(size_t)orow * EMBED + col]    = f2q8(v);
            }
        }
    }
}

// ---------------- truncated dense: 24576 batch rows ----------------
__global__ __launch_bounds__(256) void k_dense_t(const unsigned short* __restrict__ t1eS,
                                                 const unsigned short* __restrict__ embH_in,
                                                 unsigned short* __restrict__ t2out,
                                                 const unsigned short* __restrict__ Wb,
                                                 const float* __restrict__ bsum,
                                                 const int* __restrict__ u,
                                                 const int* __restrict__ ii,
                                                 const int* __restrict__ jj) {
    int tid  = threadIdx.x;
    int wave = tid >> 6, lane = tid & 63;
    int r16  = lane & 15, hi = lane >> 4;
    int rowt0 = blockIdx.x * 64 + wave * 16;             // grid = 384 exact -> bb < 24576
    int bb   = rowt0 + r16;
    int nrow = map_row(bb, u, ii, jj);

    const unsigned short* trow = t1eS    + (size_t)bb   * EMBED;
    const unsigned short* erow = embH_in + (size_t)nrow * EMBED;
    uint4 t_lo = *(const uint4*)(trow + hi * 8);
    uint4 t_hi = *(const uint4*)(trow + 32 + hi * 8);
    uint4 e_lo = *(const uint4*)(erow + hi * 8);
    uint4 e_hi = *(const uint4*)(erow + 32 + hi * 8);

    bf16x8 A0 = as_bf8(t_lo);
    bf16x8 A1 = as_bf8(t_hi);
    float ta[8], ea[8], pa[8];
    unpack8(t_lo, ta); unpack8(e_lo, ea);
#pragma unroll
    for (int j = 0; j < 8; j++) pa[j] = ta[j] * ea[j];
    bf16x8 A2 = pack8(pa);
    unpack8(t_hi, ta); unpack8(e_hi, ea);
#pragma unroll
    for (int j = 0; j < 8; j++) pa[j] = ta[j] * ea[j];
    bf16x8 A3 = pack8(pa);

#pragma unroll
    for (int nt = 0; nt < 4; nt++) {
        int wrow = nt * 16 + r16;
        const unsigned short* wp = Wb + wrow * 128 + hi * 8;
        bf16x8 B0 = as_bf8(*(const uint4*)(wp));
        bf16x8 B1 = as_bf8(*(const uint4*)(wp + 32));
        bf16x8 B2 = as_bf8(*(const uint4*)(wp + 64));
        bf16x8 B3 = as_bf8(*(const uint4*)(wp + 96));
        f32x4 c = {0.f, 0.f, 0.f, 0.f};
        c = __builtin_amdgcn_mfma_f32_16x16x32_bf16(A0, B0, c, 0, 0, 0);
        c = __builtin_amdgcn_mfma_f32_16x16x32_bf16(A1, B1, c, 0, 0, 0);
        c = __builtin_amdgcn_mfma_f32_16x16x32_bf16(A2, B2, c, 0, 0, 0);
        c = __builtin_amdgcn_mfma_f32_16x16x32_bf16(A3, B3, c, 0, 0, 0);

        int col = nt * 16 + r16;
        float bias = bsum[col];
#pragma unroll
        for (int r = 0; r < 4; r++) {
            int obb = rowt0 + hi * 4 + r;
            float v = c[r] + bias;
            v = (v > 0.f) ? v : 0.01f * v;
            t2out[(size_t)obb * EMBED + col] = f2bf(v);
        }
    }
}

// ---------------- scoring ----------------
__global__ __launch_bounds__(256) void k_score0(const float* __restrict__ ue,
                                                const float* __restrict__ ie,
                                                const int* __restrict__ u,
                                                const int* __restrict__ ii,
                                                const int* __restrict__ jj,
                                                float* __restrict__ posAcc,
                                                float* __restrict__ negAcc) {
    int wave = threadIdx.x >> 6, lane = threadIdx.x & 63;
    int b = blockIdx.x * 4 + wave;                       // grid = 2048 exact
    float eu = ue[u[b]  * EMBED + lane];
    float ep = ie[ii[b] * EMBED + lane];
    float en = ie[jj[b] * EMBED + lane];
    float p = eu * ep, n = eu * en;
    for (int o = 1; o < 64; o <<= 1) {
        p += __shfl_xor(p, o);
        n += __shfl_xor(n, o);
    }
    if (lane == 0) {
        posAcc[b] += p;
        negAcc[b] += n;
    }
}

__global__ __launch_bounds__(256) void k_score1(const unsigned short* __restrict__ tab,
                                                const int* __restrict__ u,
                                                const int* __restrict__ ii,
                                                const int* __restrict__ jj,
                                                float* __restrict__ posAcc,
                                                float* __restrict__ negAcc) {
    int wave = threadIdx.x >> 6, lane = threadIdx.x & 63;
    int b = blockIdx.x * 4 + wave;                       // grid = 2048 exact
    int ru = u[b];
    int ri = N_USERS + ii[b];
    int rj = N_USERS + jj[b];
    float eu = bf2f(tab[ru * EMBED + lane]);
    float ep = bf2f(tab[ri * EMBED + lane]);
    float en = bf2f(tab[rj * EMBED + lane]);
    float su = eu * eu, sp = ep * ep, sn = en * en;
    for (int o = 1; o < 64; o <<= 1) {
        su += __shfl_xor(su, o);
        sp += __shfl_xor(sp, o);
        sn += __shfl_xor(sn, o);
    }
    eu /= fmaxf(sqrtf(su), 1e-12f);
    ep /= fmaxf(sqrtf(sp), 1e-12f);
    en /= fmaxf(sqrtf(sn), 1e-12f);
    float p = eu * ep, n = eu * en;
    for (int o = 1; o < 64; o <<= 1) {
        p += __shfl_xor(p, o);
        n += __shfl_xor(n, o);
    }
    if (lane == 0) {
        posAcc[b] += p;
        negAcc[b] += n;
    }
}

// truncated-layer scoring: sequential reads of t2out rows (b, B+b, 2B+b)
__global__ __launch_bounds__(256) void k_score1t(const unsigned short* __restrict__ t2out,
                                                 float* __restrict__ posAcc,
                                                 float* __restrict__ negAcc) {
    int wave = threadIdx.x >> 6, lane = threadIdx.x & 63;
    int b = blockIdx.x * 4 + wave;                       // grid = 2048 exact
    float eu = bf2f(t2out[(size_t)b * EMBED + lane]);
    float ep = bf2f(t2out[(size_t)(BATCH + b) * EMBED + lane]);
    float en = bf2f(t2out[(size_t)(2 * BATCH + b) * EMBED + lane]);
    float su = eu * eu, sp = ep * ep, sn = en * en;
    for (int o = 1; o < 64; o <<= 1) {
        su += __shfl_xor(su, o);
        sp += __shfl_xor(sp, o);
        sn += __shfl_xor(sn, o);
    }
    eu /= fmaxf(sqrtf(su), 1e-12f);
    ep /= fmaxf(sqrtf(sp), 1e-12f);
    en /= fmaxf(sqrtf(sn), 1e-12f);
    float p = eu * ep, n = eu * en;
    for (int o = 1; o < 64; o <<= 1) {
        p += __shfl_xor(p, o);
        n += __shfl_xor(n, o);
    }
    if (lane == 0) {
        posAcc[b] += p;
        negAcc[b] += n;
    }
}

// ---------------- final loss ----------------
__global__ __launch_bounds__(256) void k_loss(const float* __restrict__ pa,
                                              const float* __restrict__ na,
                                              float* __restrict__ out) {
    int b = blockIdx.x * 256 + threadIdx.x;              // grid = 32 exact
    float z = pa[b] - na[b];
    float x = -z;
    float sp = fmaxf(x, 0.f) + log1pf(expf(-fabsf(x)));  // softplus(-z)
    for (int o = 1; o < 64; o <<= 1) sp += __shfl_xor(sp, o);
    __shared__ float s[4];
    int wave = threadIdx.x >> 6, lane = threadIdx.x & 63;
    if (lane == 0) s[wave] = sp;
    __syncthreads();
    if (threadIdx.x == 0) {
        float t = s[0] + s[1] + s[2] + s[3];
        atomicAdd(out, t * (1.f / (float)BATCH));
    }
}

extern "C" void kernel_launch(void* const* d_in, const int* in_sizes, int n_in,
                              void* d_out, int out_size, void* d_ws, size_t ws_size,
                              hipStream_t stream) {
    const float* user_emb = (const float*)d_in[0];
    const float* item_emb = (const float*)d_in[1];
    const float* W1       = (const float*)d_in[2];
    const float* b1       = (const float*)d_in[3];
    const float* W2       = (const float*)d_in[4];
    const float* b2       = (const float*)d_in[5];
    const float* adj_vals = (const float*)d_in[6];
    const int*   adj_rows = (const int*)d_in[7];
    const int*   adj_cols = (const int*)d_in[8];
    const int*   u_idx    = (const int*)d_in[9];
    const int*   i_idx    = (const int*)d_in[10];
    const int*   j_idx    = (const int*)d_in[11];
    float* out = (float*)d_out;

    // workspace layout (bytes) — 94,065,664 total (validated footprint)
    // region [0, 38,400,000): time-shared:
    //   CSR (first):  bucketed int2[2M] @ +0 (16,000,000), bkt_* @ +32,000,000..
    //   layers (after): t1eH @ +0 (19.2M); t1eS @ +0 / t2out @ +4M (layer 2);
    //                   Wb @ +20,000,000; bsum @ +20,100,000; Q8 @ +20,200,000 (9.6M)
    char* ws = (char*)d_ws;
    unsigned short* t1eH       = (unsigned short*)(ws);
    unsigned short* t1eS       = (unsigned short*)(ws);               // 3,145,728 B
    unsigned short* t2out      = (unsigned short*)(ws + 4000000);     // 3,145,728 B
    int2*           bucketed   = (int2*)(ws);                         // 16,000,000 B
    unsigned short* Wb         = (unsigned short*)(ws + 20000000);    // 49,152 B
    float*          bsum       = (float*)(ws + 20100000);             // 768 B
    unsigned char*  Q8         = (unsigned char*)(ws + 20200000);     // 9,600,000 B
    int*            bkt_count  = (int*)(ws + 32000000);               // 293 ints
    int*            bkt_base   = (int*)(ws + 32004096);               // 294 ints
    int*            bkt_cursor = (int*)(ws + 32008192);               // 293 ints
    unsigned short* HA         = (unsigned short*)(ws + 38400000);    // 19,200,000
    unsigned short* HB         = (unsigned short*)(ws + 57600000);    // 19,200,000
    int*            row_ptr    = (int*)(ws + 76800000);               // 600,004
    int2*           edges      = (int2*)(ws + 78000128);              // 16,000,000
    float*          posAcc     = (float*)(ws + 94000128);             // 32,768
    float*          negAcc     = (float*)(ws + 94032896);             // 32,768

    hipMemsetAsync(bkt_count, 0, 4096, stream);
    hipMemsetAsync(posAcc, 0, 2 * BATCH * sizeof(float), stream);    // covers negAcc too
    hipMemsetAsync(d_out, 0, sizeof(float), stream);

    // CSR build FIRST (bucketed region is then dead and reused by Wb/Q8)
    k_bkt_count<<<(N_EDGES / 4 + 255) / 256, 256, 0, stream>>>(adj_rows, bkt_count);
    k_bkt_scan<<<1, 512, 0, stream>>>(bkt_count, bkt_base, bkt_cursor, row_ptr);
    k_bucketA<<<(N_EDGES + EPB - 1) / EPB, 256, 0, stream>>>(adj_rows, adj_cols, adj_vals,
                                                             bkt_cursor, bucketed);
    k_bucketC<<<NBKT, 1024, 0, stream>>>(bkt_base, bucketed, row_ptr, edges);

    // weights + tables
    k_wprep<<<97, 256, 0, stream>>>(W1, b1, W2, b2, Wb, bsum);
    k_tabs<<<(N_NODES * EMBED / 4 + 255) / 256, 256, 0, stream>>>(
        (const float4*)user_emb, (const float4*)item_emb, (ushort4*)HA, (unsigned int*)Q8);

    // layer-0 scoring on raw f32 inputs (exact)
    k_score0<<<BATCH / 4, 256, 0, stream>>>(user_emb, item_emb, u_idx, i_idx, j_idx,
                                            posAcc, negAcc);

    const int SGRID = N_NODES / 4;        // 37500 (wave per row)
    const int DGRID = (N_NODES + 63) / 64;

    // layer 0: Q8(raw) -> t1eH; dense -> HB + Q8(HB)
    k_spmm<<<SGRID, 256, 0, stream>>>(row_ptr, edges, Q8, t1eH);
    k_dense<<<DGRID, 256, 0, stream>>>(t1eH, HA, HB, Q8, Wb, bsum);
    k_score1<<<BATCH / 4, 256, 0, stream>>>(HB, u_idx, i_idx, j_idx, posAcc, negAcc);

    // layer 1: Q8(HB) -> t1eH; dense -> HA + Q8(HA)
    k_spmm<<<SGRID, 256, 0, stream>>>(row_ptr, edges, Q8, t1eH);
    k_dense<<<DGRID, 256, 0, stream>>>(t1eH, HB, HA, Q8, Wb + 8192, bsum + 64);
    k_score1<<<BATCH / 4, 256, 0, stream>>>(HA, u_idx, i_idx, j_idx, posAcc, negAcc);

    // layer 2 (truncated): Q8(HA) -> t1eS -> t2out for the 24576 batch rows
    k_spmm_t<<<BATCH3 / 4, 256, 0, stream>>>(row_ptr, edges, Q8, t1eS,
                                             u_idx, i_idx, j_idx);
    k_dense_t<<<BATCH3 / 64, 256, 0, stream>>>(t1eS, HA, t2out, Wb + 16384, bsum + 128,
                                               u_idx, i_idx, j_idx);
    k_score1t<<<BATCH / 4, 256, 0, stream>>>(t2out, posAcc, negAcc);

    k_loss<<<BATCH / 256, 256, 0, stream>>>(posAcc, negAcc, out);
}